// Round 2
// baseline (13181.154 us; speedup 1.0000x reference)
//
#include <hip/hip_runtime.h>
#include <math.h>

// ---------------- problem constants ----------------
#define NIMG 32          // images per pass (x1 pass, x2 pass)
#define SENTI 147456     // H*W sentinel
#define CAPR 36864       // max 8-connected components in 384x384
#define LBG 0x7FFFFFFF   // LDS background marker

// ---------------- global union-find (device-scope safe, used on borders only) ----------------
__device__ __forceinline__ int uf_load(int* P, int i) {
  return __hip_atomic_load(&P[i], __ATOMIC_RELAXED, __HIP_MEMORY_SCOPE_AGENT);
}
__device__ int uf_find(int* P, int i) {
  int p = uf_load(P, i);
  while (p != i) {
    int gp = uf_load(P, p);
    if (gp != p) atomicMin(&P[i], gp);   // path halving, monotone decreasing => safe
    i = p; p = gp;
  }
  return i;
}
__device__ void uf_union(int* P, int a, int b) {
  while (true) {
    a = uf_find(P, a); b = uf_find(P, b);
    if (a == b) return;
    if (a > b) { int t = a; a = b; b = t; }   // a < b : attach b under a (min root wins)
    int old = atomicMin(&P[b], a);
    if (old == b) return;
    b = old;
  }
}

// ---------------- LDS union-find (tile-local) ----------------
__device__ __forceinline__ int l_load(int* lab, int i) {
  return __hip_atomic_load(&lab[i], __ATOMIC_RELAXED, __HIP_MEMORY_SCOPE_WORKGROUP);
}
__device__ int l_find(int* lab, int i) {
  int p = l_load(lab, i);
  while (p != i) { int gp = l_load(lab, p); i = p; p = gp; }
  return i;
}
__device__ void l_union(int* lab, int a, int b) {
  while (true) {
    a = l_find(lab, a); b = l_find(lab, b);
    if (a == b) return;
    if (a > b) { int t = a; a = b; b = t; }
    int old = atomicMin(&lab[b], a);
    if (old == b) return;
    b = old;
  }
}

// ---------------- conv e1: (32,1,384,384) -> (32,16,192,192), k4 s2 p1 + relu ----------------
__global__ __launch_bounds__(256) void k_conv_e1(
    const float* __restrict__ x, const float* __restrict__ w,
    const float* __restrict__ bias, float* __restrict__ out)
{
  int idx = blockIdx.x * 256 + threadIdx.x;           // 32*192*192
  int ox = idx % 192; int t = idx / 192; int oy = t % 192; int img = t / 192;
  const float* xi = x + (size_t)img * 147456;
  float acc[16];
#pragma unroll
  for (int c = 0; c < 16; c++) acc[c] = bias[c];
#pragma unroll
  for (int ky = 0; ky < 4; ky++) {
    int iy = 2 * oy + ky - 1;
    if (iy < 0 || iy >= 384) continue;
    const float* row = xi + iy * 384;
#pragma unroll
    for (int kx = 0; kx < 4; kx++) {
      int ix = 2 * ox + kx - 1;
      if (ix < 0 || ix >= 384) continue;
      float v = row[ix];
#pragma unroll
      for (int c = 0; c < 16; c++) acc[c] = fmaf(v, w[c * 16 + ky * 4 + kx], acc[c]);
    }
  }
  size_t base = (size_t)img * 589824 + (size_t)oy * 192 + ox;   // 16*36864
#pragma unroll
  for (int c = 0; c < 16; c++) out[base + (size_t)c * 36864] = fmaxf(acc[c], 0.f);
}

// ---------------- conv e2: (32,16,192,192) -> (32,32,96,96) ----------------
__global__ __launch_bounds__(256) void k_conv_e2(
    const float* __restrict__ in, const float* __restrict__ w,
    const float* __restrict__ bias, float* __restrict__ out)
{
  int idx = blockIdx.x * 256 + threadIdx.x;           // 32*96*48 (2 cols/thread)
  int p = idx % 48; int t = idx / 48; int oy = t % 96; int img = t / 96;
  const float* xin = in + (size_t)img * 589824;
  float accA[32], accB[32];
#pragma unroll
  for (int c = 0; c < 32; c++) { float bv = bias[c]; accA[c] = bv; accB[c] = bv; }
#pragma unroll 1
  for (int ci = 0; ci < 16; ci++) {
    const float* xc = xin + (size_t)ci * 36864;
#pragma unroll
    for (int ky = 0; ky < 4; ky++) {
      int iy = 2 * oy + ky - 1;
      float xv[6];
      if (iy >= 0 && iy < 192) {
        const float* row = xc + iy * 192;
        int c0 = 4 * p - 1;
#pragma unroll
        for (int u = 0; u < 6; u++) {
          int ix = c0 + u;
          xv[u] = (ix >= 0 && ix < 192) ? row[ix] : 0.f;
        }
      } else {
#pragma unroll
        for (int u = 0; u < 6; u++) xv[u] = 0.f;
      }
#pragma unroll
      for (int co = 0; co < 32; co++) {
        float4 wv = *(const float4*)(w + ((size_t)co * 16 + ci) * 16 + ky * 4);
        accA[co] = fmaf(xv[3], wv.w, fmaf(xv[2], wv.z, fmaf(xv[1], wv.y, fmaf(xv[0], wv.x, accA[co]))));
        accB[co] = fmaf(xv[5], wv.w, fmaf(xv[4], wv.z, fmaf(xv[3], wv.y, fmaf(xv[2], wv.x, accB[co]))));
      }
    }
  }
  size_t base = (size_t)img * 294912 + (size_t)oy * 96 + 2 * p;  // 32*9216
#pragma unroll
  for (int co = 0; co < 32; co++) {
    float2 v; v.x = fmaxf(accA[co], 0.f); v.y = fmaxf(accB[co], 0.f);
    *(float2*)(out + base + (size_t)co * 9216) = v;
  }
}

// ---------------- conv e3: (32,32,96,96) -> (32,64,48,48), co split in 2 groups ----------------
__global__ __launch_bounds__(256) void k_conv_e3(
    const float* __restrict__ in, const float* __restrict__ w,
    const float* __restrict__ bias, float* __restrict__ out)
{
  int idx = blockIdx.x * 256 + threadIdx.x;           // 32*48*24
  int cog = blockIdx.y;                               // 0/1 -> co groups of 32
  int p = idx % 24; int t = idx / 24; int oy = t % 48; int img = t / 48;
  const float* xin = in + (size_t)img * 294912;
  float accA[32], accB[32];
#pragma unroll
  for (int c = 0; c < 32; c++) { float bv = bias[cog * 32 + c]; accA[c] = bv; accB[c] = bv; }
#pragma unroll 1
  for (int ci = 0; ci < 32; ci++) {
    const float* xc = xin + (size_t)ci * 9216;
#pragma unroll
    for (int ky = 0; ky < 4; ky++) {
      int iy = 2 * oy + ky - 1;
      float xv[6];
      if (iy >= 0 && iy < 96) {
        const float* row = xc + iy * 96;
        int c0 = 4 * p - 1;
#pragma unroll
        for (int u = 0; u < 6; u++) {
          int ix = c0 + u;
          xv[u] = (ix >= 0 && ix < 96) ? row[ix] : 0.f;
        }
      } else {
#pragma unroll
        for (int u = 0; u < 6; u++) xv[u] = 0.f;
      }
#pragma unroll
      for (int co = 0; co < 32; co++) {
        float4 wv = *(const float4*)(w + ((size_t)(cog * 32 + co) * 32 + ci) * 16 + ky * 4);
        accA[co] = fmaf(xv[3], wv.w, fmaf(xv[2], wv.z, fmaf(xv[1], wv.y, fmaf(xv[0], wv.x, accA[co]))));
        accB[co] = fmaf(xv[5], wv.w, fmaf(xv[4], wv.z, fmaf(xv[3], wv.y, fmaf(xv[2], wv.x, accB[co]))));
      }
    }
  }
  size_t base = (size_t)img * 147456 + (size_t)(cog * 32) * 2304 + (size_t)oy * 48 + 2 * p;
#pragma unroll
  for (int co = 0; co < 32; co++) {
    float2 v; v.x = fmaxf(accA[co], 0.f); v.y = fmaxf(accB[co], 0.f);
    *(float2*)(out + base + (size_t)co * 2304) = v;
  }
}

// ---------------- convT d3: (32,64,48,48) -> (32,32,96,96), w (64,32,4,4) ----------------
__global__ __launch_bounds__(256) void k_convt_d3(
    const float* __restrict__ in, const float* __restrict__ w,
    const float* __restrict__ bias, float* __restrict__ out)
{
  int idx = blockIdx.x * 256 + threadIdx.x;           // 32*96*48
  int p = idx % 48; int t = idx / 48; int oy = t % 96; int img = t / 96;
  int iy1 = (oy + 1) >> 1; int iy0 = iy1 - 1;
  int ky1 = (oy + 1) - 2 * iy1; int ky0 = ky1 + 2;    // ky1 in {0,1}
  bool v1 = (iy1 < 48), v0 = (iy0 >= 0);
  bool pm = (p > 0), pp = (p < 47);
  float accA[32], accB[32];
#pragma unroll
  for (int c = 0; c < 32; c++) { float bv = bias[c]; accA[c] = bv; accB[c] = bv; }
#pragma unroll 1
  for (int ci = 0; ci < 64; ci++) {
    const float* xc = in + (size_t)img * 147456 + (size_t)ci * 2304;
    const float* r1 = xc + iy1 * 48; const float* r0 = xc + iy0 * 48;
    float x1m = (v1 && pm) ? r1[p - 1] : 0.f;
    float x1c = v1 ? r1[p] : 0.f;
    float x1p = (v1 && pp) ? r1[p + 1] : 0.f;
    float x0m = (v0 && pm) ? r0[p - 1] : 0.f;
    float x0c = v0 ? r0[p] : 0.f;
    float x0p = (v0 && pp) ? r0[p + 1] : 0.f;
    const float* wb = w + (size_t)ci * 512;           // ci*32*16
#pragma unroll
    for (int co = 0; co < 32; co++) {
      float4 wv1 = *(const float4*)(wb + co * 16 + ky1 * 4);
      float4 wv0 = *(const float4*)(wb + co * 16 + ky0 * 4);
      accA[co] += x1c * wv1.y + x1m * wv1.w + x0c * wv0.y + x0m * wv0.w;
      accB[co] += x1p * wv1.x + x1c * wv1.z + x0p * wv0.x + x0c * wv0.z;
    }
  }
  size_t base = (size_t)img * 294912 + (size_t)oy * 96 + 2 * p;
#pragma unroll
  for (int co = 0; co < 32; co++) {
    float2 v; v.x = fmaxf(accA[co], 0.f); v.y = fmaxf(accB[co], 0.f);
    *(float2*)(out + base + (size_t)co * 9216) = v;
  }
}

// ---------------- convT d2 (dual src): [D3 | E2] (32,64,96,96) -> (32,16,192,192), w (64,16,4,4) ----------------
__global__ __launch_bounds__(256) void k_convt_d2(
    const float* __restrict__ d3, const float* __restrict__ e2,
    const float* __restrict__ w, const float* __restrict__ bias,
    float* __restrict__ out)
{
  int idx = blockIdx.x * 256 + threadIdx.x;           // 32*192*96
  int p = idx % 96; int t = idx / 96; int oy = t % 192; int img = t / 192;
  int iy1 = (oy + 1) >> 1; int iy0 = iy1 - 1;
  int ky1 = (oy + 1) - 2 * iy1; int ky0 = ky1 + 2;
  bool v1 = (iy1 < 96), v0 = (iy0 >= 0);
  bool pm = (p > 0), pp = (p < 95);
  float accA[16], accB[16];
#pragma unroll
  for (int c = 0; c < 16; c++) { float bv = bias[c]; accA[c] = bv; accB[c] = bv; }
  for (int half = 0; half < 2; half++) {
    const float* src = (half == 0) ? d3 : e2;
#pragma unroll 1
    for (int ci = 0; ci < 32; ci++) {
      const float* xc = src + (size_t)img * 294912 + (size_t)ci * 9216;
      const float* r1 = xc + iy1 * 96; const float* r0 = xc + iy0 * 96;
      float x1m = (v1 && pm) ? r1[p - 1] : 0.f;
      float x1c = v1 ? r1[p] : 0.f;
      float x1p = (v1 && pp) ? r1[p + 1] : 0.f;
      float x0m = (v0 && pm) ? r0[p - 1] : 0.f;
      float x0c = v0 ? r0[p] : 0.f;
      float x0p = (v0 && pp) ? r0[p + 1] : 0.f;
      const float* wb = w + (size_t)(half * 32 + ci) * 256;  // ci_glob*16*16
#pragma unroll
      for (int co = 0; co < 16; co++) {
        float4 wv1 = *(const float4*)(wb + co * 16 + ky1 * 4);
        float4 wv0 = *(const float4*)(wb + co * 16 + ky0 * 4);
        accA[co] += x1c * wv1.y + x1m * wv1.w + x0c * wv0.y + x0m * wv0.w;
        accB[co] += x1p * wv1.x + x1c * wv1.z + x0p * wv0.x + x0c * wv0.z;
      }
    }
  }
  size_t base = (size_t)img * 589824 + (size_t)oy * 192 + 2 * p;  // 16*36864
#pragma unroll
  for (int co = 0; co < 16; co++) {
    float2 v; v.x = fmaxf(accA[co], 0.f); v.y = fmaxf(accB[co], 0.f);
    *(float2*)(out + base + (size_t)co * 36864) = v;
  }
}

// ---------------- convT d1 (dual src) + sigmoid-threshold -> parent init ----------------
__global__ __launch_bounds__(256) void k_convt_d1(
    const float* __restrict__ d2, const float* __restrict__ e1,
    const float* __restrict__ w, const float* __restrict__ bias,
    int* __restrict__ parent)
{
  int idx = blockIdx.x * 256 + threadIdx.x;           // 32*384*192
  int p = idx % 192; int t = idx / 192; int oy = t % 384; int img = t / 384;
  int iy1 = (oy + 1) >> 1; int iy0 = iy1 - 1;
  int ky1 = (oy + 1) - 2 * iy1; int ky0 = ky1 + 2;
  bool v1 = (iy1 < 192), v0 = (iy0 >= 0);
  bool pm = (p > 0), pp = (p < 191);
  float zA = bias[0], zB = bias[0];
  for (int half = 0; half < 2; half++) {
    const float* src = (half == 0) ? d2 : e1;
#pragma unroll 1
    for (int ci = 0; ci < 16; ci++) {
      const float* xc = src + (size_t)img * 589824 + (size_t)ci * 36864;
      const float* r1 = xc + iy1 * 192; const float* r0 = xc + iy0 * 192;
      float x1m = (v1 && pm) ? r1[p - 1] : 0.f;
      float x1c = v1 ? r1[p] : 0.f;
      float x1p = (v1 && pp) ? r1[p + 1] : 0.f;
      float x0m = (v0 && pm) ? r0[p - 1] : 0.f;
      float x0c = v0 ? r0[p] : 0.f;
      float x0p = (v0 && pp) ? r0[p + 1] : 0.f;
      const float* wb = w + (size_t)(half * 16 + ci) * 16;   // (32,1,4,4)
      float4 wv1 = *(const float4*)(wb + ky1 * 4);
      float4 wv0 = *(const float4*)(wb + ky0 * 4);
      zA += x1c * wv1.y + x1m * wv1.w + x0c * wv0.y + x0m * wv0.w;
      zB += x1p * wv1.x + x1c * wv1.z + x0p * wv0.x + x0c * wv0.z;
    }
  }
  // sigmoid(z) > 0.75  <=>  z > ln(3)
  const float LN3 = 1.0986122886681098f;
  int* P = parent + (size_t)img * SENTI;
  int pixA = oy * 384 + 2 * p;
  P[pixA]     = (zA > LN3) ? pixA : SENTI;
  P[pixA + 1] = (zB > LN3) ? (pixA + 1) : SENTI;
}

// ---------------- tile-local CCL: 32x32 tiles, union-find in LDS ----------------
__global__ __launch_bounds__(256) void k_tile_uf(int* __restrict__ parent)
{
  __shared__ int lab[1024];
  int img = blockIdx.y;
  int tile = blockIdx.x;                              // 0..143
  int tx = tile % 12, ty = tile / 12;
  int tid = threadIdx.x;
  int* P = parent + (size_t)img * SENTI;
  int gbase = (ty * 32) * 384 + tx * 32;
  bool fg[4];
#pragma unroll
  for (int s = 0; s < 4; s++) {
    int c = tid + s * 256;
    int ly = c >> 5, lx = c & 31;
    int v = P[gbase + ly * 384 + lx];
    fg[s] = (v < SENTI);
    lab[c] = fg[s] ? c : LBG;
  }
  __syncthreads();
#pragma unroll
  for (int s = 0; s < 4; s++) {
    int c = tid + s * 256;
    if (!fg[s]) continue;
    int ly = c >> 5, lx = c & 31;
    if (lx > 0              && l_load(lab, c - 1)  != LBG) l_union(lab, c, c - 1);
    if (ly > 0) {
      if (                     l_load(lab, c - 32) != LBG) l_union(lab, c, c - 32);
      if (lx > 0            && l_load(lab, c - 33) != LBG) l_union(lab, c, c - 33);
      if (lx < 31           && l_load(lab, c - 31) != LBG) l_union(lab, c, c - 31);
    }
  }
  __syncthreads();
#pragma unroll
  for (int s = 0; s < 4; s++) {
    int c = tid + s * 256;
    if (!fg[s]) continue;
    int rc = c, q = lab[rc];
    while (q != rc) { rc = q; q = lab[rc]; }          // structure frozen after barrier
    int rly = rc >> 5, rlx = rc & 31;
    int ly = c >> 5, lx = c & 31;
    P[gbase + ly * 384 + lx] = gbase + rly * 384 + rlx;
  }
}

// ---------------- border merge: unions only across 32-aligned tile edges ----------------
__global__ __launch_bounds__(256) void k_border(int* __restrict__ parent)
{
  int idx = blockIdx.x * 256 + threadIdx.x;           // 32*147456
  int img = idx / SENTI; int p = idx - img * SENTI;
  int* P = parent + (size_t)img * SENTI;
  int x = p % 384; int y = p / 384;
  bool bx = ((x & 31) == 0) && x > 0;
  bool by = ((y & 31) == 0) && y > 0;
  if (!bx && !by) return;
  if (P[p] >= SENTI) return;
  if (bx) {
    if (            P[p - 1]   < SENTI) uf_union(P, p, p - 1);
    if (y > 0   &&  P[p - 385] < SENTI) uf_union(P, p, p - 385);
    if (y < 383 &&  P[p + 383] < SENTI) uf_union(P, p, p + 383);
  }
  if (by) {
    if (            P[p - 384] < SENTI) uf_union(P, p, p - 384);
    if (x > 0   &&  P[p - 385] < SENTI) uf_union(P, p, p - 385);
    if (x < 383 &&  P[p - 383] < SENTI) uf_union(P, p, p - 383);
  }
}

// ---------------- flatten + collect roots (plain loads; chains are short) ----------------
__global__ __launch_bounds__(256) void k_flatten(
    int* __restrict__ parent, int* __restrict__ rootCnt,
    int* __restrict__ rootList, int base)
{
  int idx = blockIdx.x * 256 + threadIdx.x;
  int img = idx / SENTI; int p = idx - img * SENTI;
  int* P = parent + (size_t)img * SENTI;
  int v = P[p];
  if (v >= SENTI) return;
  int r = v, q = P[r];
  while (q != r) { r = q; q = P[r]; }                 // labels strictly decrease -> terminates
  P[p] = r;
  if (r == p) {
    int s = atomicAdd(&rootCnt[base + img], 1);
    if (s < CAPR) rootList[(size_t)img * CAPR + s] = p;
  }
}

// ---------------- select K smallest roots per image ----------------
__global__ __launch_bounds__(256) void k_select(
    const int* __restrict__ rootCnt, const int* __restrict__ rootList,
    int* __restrict__ U, int* __restrict__ NC, int base)
{
  int img = blockIdx.x; int tid = threadIdx.x;
  __shared__ int sv[256];
  int m = rootCnt[base + img]; if (m > CAPR) m = CAPR;
  const int* rl = rootList + (size_t)img * CAPR;
  int prev = -1;
  for (int k = 0; k < 16; k++) {
    int best = SENTI;
    for (int i = tid; i < m; i += 256) {
      int v = rl[i];
      if (v > prev && v < best) best = v;
    }
    sv[tid] = best; __syncthreads();
    for (int s = 128; s > 0; s >>= 1) {
      if (tid < s) sv[tid] = min(sv[tid], sv[tid + s]);
      __syncthreads();
    }
    int sel = sv[0];
    if (tid == 0) U[(base + img) * 16 + k] = sel;
    prev = (sel < SENTI) ? sel : 0x7FFF0000;          // once exhausted, stay SENT
    __syncthreads();
  }
  if (tid == 0) NC[base + img] = (m < 16) ? m : 16;
}

// ---------------- per-component centroid stats ----------------
__global__ __launch_bounds__(256) void k_stats(
    const int* __restrict__ parent, const int* __restrict__ U,
    int* __restrict__ CNT, float* __restrict__ SX, float* __restrict__ SY, int base)
{
  __shared__ int lc[16]; __shared__ float lx[16], ly[16];
  int tid = threadIdx.x;
  if (tid < 16) { lc[tid] = 0; lx[tid] = 0.f; ly[tid] = 0.f; }
  __syncthreads();
  int img = blockIdx.y; int g = base + img;
  int p = blockIdx.x * 256 + tid;                     // 576*256 = 147456
  int lbl = parent[(size_t)img * SENTI + p];
  if (lbl < SENTI) {
    const int* u = U + g * 16;
    int slot = -1;
#pragma unroll
    for (int s = 0; s < 16; s++) if (u[s] == lbl) slot = s;
    if (slot >= 0) {
      atomicAdd(&lc[slot], 1);
      atomicAdd(&lx[slot], (float)(p % 384));
      atomicAdd(&ly[slot], (float)(p / 384));
    }
  }
  __syncthreads();
  if (tid < 16 && lc[tid] > 0) {
    atomicAdd(&CNT[g * 16 + tid], lc[tid]);
    atomicAdd(&SX[g * 16 + tid], lx[tid]);
    atomicAdd(&SY[g * 16 + tid], ly[tid]);
  }
}

// ---------------- polar sort + greedy match + MLP ----------------
__global__ __launch_bounds__(64) void k_final(
    const int* __restrict__ U, const int* __restrict__ NC,
    const int* __restrict__ CNT, const float* __restrict__ SX,
    const float* __restrict__ SY,
    const float* __restrict__ w1, const float* __restrict__ b1,
    const float* __restrict__ w2, const float* __restrict__ b2,
    const float* __restrict__ w3, const float* __restrict__ b3,
    float* __restrict__ out)
{
  int b = threadIdx.x;
  if (b >= 32) return;
  const float INF = __builtin_inff();
  float R[2][16], A[2][16]; int N[2];
  for (int side = 0; side < 2; side++) {
    int img = b + side * 32;
    float rr[16], aa[16], key[16];
    for (int s = 0; s < 16; s++) {
      bool valid = U[img * 16 + s] < SENTI;
      float c = fmaxf((float)CNT[img * 16 + s], 1.f);
      float cx = SX[img * 16 + s] / c, cy = SY[img * 16 + s] / c;
      float dx = cx - 192.f, dy = cy - 192.f;
      rr[s] = sqrtf(dx * dx + dy * dy);
      float ang = atan2f(dy, dx) * 57.29577951308232f;   // rad2deg
      ang = fmodf(ang, 360.f);
      if (ang < 0.f) ang += 360.f;                       // python % semantics
      aa[s] = ang;
      key[s] = valid ? rr[s] : INF;
    }
    bool taken[16];
    for (int s = 0; s < 16; s++) taken[s] = false;
    for (int k = 0; k < 16; k++) {                       // stable selection sort by (key, idx)
      int bi = -1; float bk = 0.f;
      for (int s = 0; s < 16; s++) {
        if (taken[s]) continue;
        if (bi < 0 || key[s] < bk) { bi = s; bk = key[s]; }
      }
      taken[bi] = true;
      bool val = (key[bi] < INF);
      R[side][k] = val ? rr[bi] : 0.f;
      A[side][k] = val ? aa[bi] : 0.f;
    }
    N[side] = NC[img];
  }
  // greedy nearest-radius matching (A = smaller-or-equal set)
  int n1 = N[0], n2 = N[1];
  bool sw = n1 > n2;
  float* rA = sw ? R[1] : R[0];
  float* aA = sw ? A[1] : A[0];
  float* rB = sw ? R[0] : R[1];
  float* aB = sw ? A[0] : A[1];
  int nA = sw ? n2 : n1;
  int nB = sw ? n1 : n2;
  bool used[16];
  for (int s = 0; s < 16; s++) used[s] = false;
  float f[32];
  for (int i = 0; i < 16; i++) {
    bool vi = i < nA;
    float best = 0.f; int j = 0; bool found = false;
    for (int jj = 0; jj < 16; jj++) {
      if (used[jj] || jj >= nB) continue;
      float d = fabsf(rB[jj] - rA[i]);
      if (!found || d < best) { best = d; j = jj; found = true; }
    }
    float dr = rA[i] - rB[j];
    float da = fabsf(sinf((aA[i] - aB[j]) * 0.017453292519943295f));  // deg2rad
    f[2 * i]     = vi ? dr : 0.f;
    f[2 * i + 1] = vi ? da : 0.f;
    if (vi) used[j] = true;
  }
  // MLP 32 -> 32 -> 8 -> 1
  float h1[32];
  for (int jj = 0; jj < 32; jj++) {
    float s = b1[jj];
    for (int k2 = 0; k2 < 32; k2++) s += w1[jj * 32 + k2] * f[k2];
    h1[jj] = fmaxf(s, 0.f);
  }
  float h2[8];
  for (int jj = 0; jj < 8; jj++) {
    float s = b2[jj];
    for (int k2 = 0; k2 < 32; k2++) s += w2[jj * 32 + k2] * h1[k2];
    h2[jj] = fmaxf(s, 0.f);
  }
  float o = b3[0];
  for (int k2 = 0; k2 < 8; k2++) o += w3[k2] * h2[k2];
  out[b] = o;
}

// ---------------- host ----------------
extern "C" void kernel_launch(void* const* d_in, const int* in_sizes, int n_in,
                              void* d_out, int out_size, void* d_ws, size_t ws_size,
                              hipStream_t stream)
{
  (void)in_sizes; (void)n_in; (void)out_size; (void)ws_size;
  const float* x1  = (const float*)d_in[0];
  const float* x2  = (const float*)d_in[1];
  const float* e1w = (const float*)d_in[2];  const float* e1b = (const float*)d_in[3];
  const float* e2w = (const float*)d_in[4];  const float* e2b = (const float*)d_in[5];
  const float* e3w = (const float*)d_in[6];  const float* e3b = (const float*)d_in[7];
  const float* d3w = (const float*)d_in[8];  const float* d3b = (const float*)d_in[9];
  const float* d2w = (const float*)d_in[10]; const float* d2b = (const float*)d_in[11];
  const float* d1w = (const float*)d_in[12]; const float* d1b = (const float*)d_in[13];
  const float* w1  = (const float*)d_in[14]; const float* b1  = (const float*)d_in[15];
  const float* w2  = (const float*)d_in[16]; const float* b2  = (const float*)d_in[17];
  const float* w3  = (const float*)d_in[18]; const float* b3  = (const float*)d_in[19];

  // workspace layout (two half-batch passes; peak ~245.4 MB)
  char* ws = (char*)d_ws;
  float* E1 = (float*)(ws + 0);                       //  75,497,472 B (32,16,192,192)
  float* E2 = (float*)(ws + 75497472);                //  37,748,736 B (32,32,96,96)
  float* E3 = (float*)(ws + 113246208);               //  18,874,368 B (32,64,48,48)
  float* D3 = (float*)(ws + 132120576);               //  37,748,736 B (32,32,96,96)
  float* D2 = (float*)(ws + 169869312);               //  75,497,472 B (32,16,192,192)
  char* small = ws + 245366784;
  int* PARENT = (int*)E3;                             // alias: E3 dead after d3
  int* ROOTL  = (int*)E2;                             // alias: E2 dead after d2
  int*   ROOTC = (int*)(small);                       // 64 ints
  int*   U     = (int*)(small + 256);                 // 64*16 ints
  int*   NC    = (int*)(small + 4352);                // 64 ints
  int*   CNT   = (int*)(small + 4608);                // 64*16 ints
  float* SX    = (float*)(small + 8704);              // 64*16 f
  float* SY    = (float*)(small + 12800);             // 64*16 f

  hipMemsetAsync(ROOTC, 0, 256, stream);
  hipMemsetAsync(CNT, 0, 4096, stream);
  hipMemsetAsync(SX, 0, 4096, stream);
  hipMemsetAsync(SY, 0, 4096, stream);

  for (int pass = 0; pass < 2; pass++) {
    const float* x = (pass == 0) ? x1 : x2;
    int base = pass * 32;
    k_conv_e1<<<4608, 256, 0, stream>>>(x, e1w, e1b, E1);
    k_conv_e2<<<576, 256, 0, stream>>>(E1, e2w, e2b, E2);
    k_conv_e3<<<dim3(144, 2), 256, 0, stream>>>(E2, e3w, e3b, E3);
    k_convt_d3<<<576, 256, 0, stream>>>(E3, d3w, d3b, D3);
    k_convt_d2<<<2304, 256, 0, stream>>>(D3, E2, d2w, d2b, D2);
    k_convt_d1<<<9216, 256, 0, stream>>>(D2, E1, d1w, d1b, PARENT);
    k_tile_uf<<<dim3(144, 32), 256, 0, stream>>>(PARENT);
    k_border<<<18432, 256, 0, stream>>>(PARENT);
    k_flatten<<<18432, 256, 0, stream>>>(PARENT, ROOTC, ROOTL, base);
    k_select<<<32, 256, 0, stream>>>(ROOTC, ROOTL, U, NC, base);
    k_stats<<<dim3(576, 32), 256, 0, stream>>>(PARENT, U, CNT, SX, SY, base);
  }
  k_final<<<1, 64, 0, stream>>>(U, NC, CNT, SX, SY, w1, b1, w2, b2, w3, b3, (float*)d_out);
}

// Round 3
// 4166.843 us; speedup vs baseline: 3.1633x; 3.1633x over previous
//
#include <hip/hip_runtime.h>
#include <math.h>

// ---------------- problem constants ----------------
#define NIMG 32          // images per pass (x1 pass, x2 pass)
#define SENTI 147456     // H*W sentinel
#define CAPR 36864       // max 8-connected components in 384x384
#define LBG 0x7FFFFFFF   // LDS background marker

// ---------------- global union-find (device-scope safe, used on borders only) ----------------
__device__ __forceinline__ int uf_load(int* P, int i) {
  return __hip_atomic_load(&P[i], __ATOMIC_RELAXED, __HIP_MEMORY_SCOPE_AGENT);
}
__device__ int uf_find(int* P, int i) {
  int p = uf_load(P, i);
  while (p != i) {
    int gp = uf_load(P, p);
    if (gp != p) atomicMin(&P[i], gp);   // path halving, monotone decreasing => safe
    i = p; p = gp;
  }
  return i;
}
__device__ void uf_union(int* P, int a, int b) {
  while (true) {
    a = uf_find(P, a); b = uf_find(P, b);
    if (a == b) return;
    if (a > b) { int t = a; a = b; b = t; }   // a < b : attach b under a (min root wins)
    int old = atomicMin(&P[b], a);
    if (old == b) return;
    b = old;
  }
}

// ---------------- LDS union-find (tile-local) ----------------
__device__ __forceinline__ int l_load(int* lab, int i) {
  return __hip_atomic_load(&lab[i], __ATOMIC_RELAXED, __HIP_MEMORY_SCOPE_WORKGROUP);
}
__device__ int l_find(int* lab, int i) {
  int p = l_load(lab, i);
  while (p != i) { int gp = l_load(lab, p); i = p; p = gp; }
  return i;
}
__device__ void l_union(int* lab, int a, int b) {
  while (true) {
    a = l_find(lab, a); b = l_find(lab, b);
    if (a == b) return;
    if (a > b) { int t = a; a = b; b = t; }
    int old = atomicMin(&lab[b], a);
    if (old == b) return;
    b = old;
  }
}

// ---------------- conv e1: (32,1,384,384) -> (32,16,192,192), k4 s2 p1 + relu ----------------
__global__ __launch_bounds__(256) void k_conv_e1(
    const float* __restrict__ x, const float* __restrict__ w,
    const float* __restrict__ bias, float* __restrict__ out)
{
  int idx = blockIdx.x * 256 + threadIdx.x;           // 32*192*192
  int ox = idx % 192; int t = idx / 192; int oy = t % 192; int img = t / 192;
  const float* xi = x + (size_t)img * 147456;
  float acc[16];
#pragma unroll
  for (int c = 0; c < 16; c++) acc[c] = bias[c];
#pragma unroll
  for (int ky = 0; ky < 4; ky++) {
    int iy = 2 * oy + ky - 1;
    if (iy < 0 || iy >= 384) continue;
    const float* row = xi + iy * 384;
#pragma unroll
    for (int kx = 0; kx < 4; kx++) {
      int ix = 2 * ox + kx - 1;
      if (ix < 0 || ix >= 384) continue;
      float v = row[ix];
#pragma unroll
      for (int c = 0; c < 16; c++) acc[c] = fmaf(v, w[c * 16 + ky * 4 + kx], acc[c]);
    }
  }
  size_t base = (size_t)img * 589824 + (size_t)oy * 192 + ox;   // 16*36864
#pragma unroll
  for (int c = 0; c < 16; c++) out[base + (size_t)c * 36864] = fmaxf(acc[c], 0.f);
}

// ---------------- conv e2: (32,16,192,192) -> (32,32,96,96) ----------------
__global__ __launch_bounds__(256) void k_conv_e2(
    const float* __restrict__ in, const float* __restrict__ w,
    const float* __restrict__ bias, float* __restrict__ out)
{
  int idx = blockIdx.x * 256 + threadIdx.x;           // 32*96*48 (2 cols/thread)
  int p = idx % 48; int t = idx / 48; int oy = t % 96; int img = t / 96;
  const float* xin = in + (size_t)img * 589824;
  float accA[32], accB[32];
#pragma unroll
  for (int c = 0; c < 32; c++) { float bv = bias[c]; accA[c] = bv; accB[c] = bv; }
#pragma unroll 1
  for (int ci = 0; ci < 16; ci++) {
    const float* xc = xin + (size_t)ci * 36864;
#pragma unroll
    for (int ky = 0; ky < 4; ky++) {
      int iy = 2 * oy + ky - 1;
      float xv[6];
      if (iy >= 0 && iy < 192) {
        const float* row = xc + iy * 192;
        int c0 = 4 * p - 1;
#pragma unroll
        for (int u = 0; u < 6; u++) {
          int ix = c0 + u;
          xv[u] = (ix >= 0 && ix < 192) ? row[ix] : 0.f;
        }
      } else {
#pragma unroll
        for (int u = 0; u < 6; u++) xv[u] = 0.f;
      }
#pragma unroll
      for (int co = 0; co < 32; co++) {
        float4 wv = *(const float4*)(w + ((size_t)co * 16 + ci) * 16 + ky * 4);
        accA[co] = fmaf(xv[3], wv.w, fmaf(xv[2], wv.z, fmaf(xv[1], wv.y, fmaf(xv[0], wv.x, accA[co]))));
        accB[co] = fmaf(xv[5], wv.w, fmaf(xv[4], wv.z, fmaf(xv[3], wv.y, fmaf(xv[2], wv.x, accB[co]))));
      }
    }
  }
  size_t base = (size_t)img * 294912 + (size_t)oy * 96 + 2 * p;  // 32*9216
#pragma unroll
  for (int co = 0; co < 32; co++) {
    float2 v; v.x = fmaxf(accA[co], 0.f); v.y = fmaxf(accB[co], 0.f);
    *(float2*)(out + base + (size_t)co * 9216) = v;
  }
}

// ---------------- conv e3: (32,32,96,96) -> (32,64,48,48), co split in 2 groups ----------------
__global__ __launch_bounds__(256) void k_conv_e3(
    const float* __restrict__ in, const float* __restrict__ w,
    const float* __restrict__ bias, float* __restrict__ out)
{
  int idx = blockIdx.x * 256 + threadIdx.x;           // 32*48*24
  int cog = blockIdx.y;                               // 0/1 -> co groups of 32
  int p = idx % 24; int t = idx / 24; int oy = t % 48; int img = t / 48;
  const float* xin = in + (size_t)img * 294912;
  float accA[32], accB[32];
#pragma unroll
  for (int c = 0; c < 32; c++) { float bv = bias[cog * 32 + c]; accA[c] = bv; accB[c] = bv; }
#pragma unroll 1
  for (int ci = 0; ci < 32; ci++) {
    const float* xc = xin + (size_t)ci * 9216;
#pragma unroll
    for (int ky = 0; ky < 4; ky++) {
      int iy = 2 * oy + ky - 1;
      float xv[6];
      if (iy >= 0 && iy < 96) {
        const float* row = xc + iy * 96;
        int c0 = 4 * p - 1;
#pragma unroll
        for (int u = 0; u < 6; u++) {
          int ix = c0 + u;
          xv[u] = (ix >= 0 && ix < 96) ? row[ix] : 0.f;
        }
      } else {
#pragma unroll
        for (int u = 0; u < 6; u++) xv[u] = 0.f;
      }
#pragma unroll
      for (int co = 0; co < 32; co++) {
        float4 wv = *(const float4*)(w + ((size_t)(cog * 32 + co) * 32 + ci) * 16 + ky * 4);
        accA[co] = fmaf(xv[3], wv.w, fmaf(xv[2], wv.z, fmaf(xv[1], wv.y, fmaf(xv[0], wv.x, accA[co]))));
        accB[co] = fmaf(xv[5], wv.w, fmaf(xv[4], wv.z, fmaf(xv[3], wv.y, fmaf(xv[2], wv.x, accB[co]))));
      }
    }
  }
  size_t base = (size_t)img * 147456 + (size_t)(cog * 32) * 2304 + (size_t)oy * 48 + 2 * p;
#pragma unroll
  for (int co = 0; co < 32; co++) {
    float2 v; v.x = fmaxf(accA[co], 0.f); v.y = fmaxf(accB[co], 0.f);
    *(float2*)(out + base + (size_t)co * 2304) = v;
  }
}

// ---------------- convT d3: (32,64,48,48) -> (32,32,96,96), w (64,32,4,4) ----------------
__global__ __launch_bounds__(256) void k_convt_d3(
    const float* __restrict__ in, const float* __restrict__ w,
    const float* __restrict__ bias, float* __restrict__ out)
{
  int idx = blockIdx.x * 256 + threadIdx.x;           // 32*96*48
  int p = idx % 48; int t = idx / 48; int oy = t % 96; int img = t / 96;
  int iy1 = (oy + 1) >> 1; int iy0 = iy1 - 1;
  int ky1 = (oy + 1) - 2 * iy1; int ky0 = ky1 + 2;    // ky1 in {0,1}
  bool v1 = (iy1 < 48), v0 = (iy0 >= 0);
  bool pm = (p > 0), pp = (p < 47);
  float accA[32], accB[32];
#pragma unroll
  for (int c = 0; c < 32; c++) { float bv = bias[c]; accA[c] = bv; accB[c] = bv; }
#pragma unroll 1
  for (int ci = 0; ci < 64; ci++) {
    const float* xc = in + (size_t)img * 147456 + (size_t)ci * 2304;
    const float* r1 = xc + iy1 * 48; const float* r0 = xc + iy0 * 48;
    float x1m = (v1 && pm) ? r1[p - 1] : 0.f;
    float x1c = v1 ? r1[p] : 0.f;
    float x1p = (v1 && pp) ? r1[p + 1] : 0.f;
    float x0m = (v0 && pm) ? r0[p - 1] : 0.f;
    float x0c = v0 ? r0[p] : 0.f;
    float x0p = (v0 && pp) ? r0[p + 1] : 0.f;
    const float* wb = w + (size_t)ci * 512;           // ci*32*16
#pragma unroll
    for (int co = 0; co < 32; co++) {
      float4 wv1 = *(const float4*)(wb + co * 16 + ky1 * 4);
      float4 wv0 = *(const float4*)(wb + co * 16 + ky0 * 4);
      accA[co] += x1c * wv1.y + x1m * wv1.w + x0c * wv0.y + x0m * wv0.w;
      accB[co] += x1p * wv1.x + x1c * wv1.z + x0p * wv0.x + x0c * wv0.z;
    }
  }
  size_t base = (size_t)img * 294912 + (size_t)oy * 96 + 2 * p;
#pragma unroll
  for (int co = 0; co < 32; co++) {
    float2 v; v.x = fmaxf(accA[co], 0.f); v.y = fmaxf(accB[co], 0.f);
    *(float2*)(out + base + (size_t)co * 9216) = v;
  }
}

// ---------------- convT d2 (dual src): [D3 | E2] (32,64,96,96) -> (32,16,192,192), w (64,16,4,4) ----------------
__global__ __launch_bounds__(256) void k_convt_d2(
    const float* __restrict__ d3, const float* __restrict__ e2,
    const float* __restrict__ w, const float* __restrict__ bias,
    float* __restrict__ out)
{
  int idx = blockIdx.x * 256 + threadIdx.x;           // 32*192*96
  int p = idx % 96; int t = idx / 96; int oy = t % 192; int img = t / 192;
  int iy1 = (oy + 1) >> 1; int iy0 = iy1 - 1;
  int ky1 = (oy + 1) - 2 * iy1; int ky0 = ky1 + 2;
  bool v1 = (iy1 < 96), v0 = (iy0 >= 0);
  bool pm = (p > 0), pp = (p < 95);
  float accA[16], accB[16];
#pragma unroll
  for (int c = 0; c < 16; c++) { float bv = bias[c]; accA[c] = bv; accB[c] = bv; }
  for (int half = 0; half < 2; half++) {
    const float* src = (half == 0) ? d3 : e2;
#pragma unroll 1
    for (int ci = 0; ci < 32; ci++) {
      const float* xc = src + (size_t)img * 294912 + (size_t)ci * 9216;
      const float* r1 = xc + iy1 * 96; const float* r0 = xc + iy0 * 96;
      float x1m = (v1 && pm) ? r1[p - 1] : 0.f;
      float x1c = v1 ? r1[p] : 0.f;
      float x1p = (v1 && pp) ? r1[p + 1] : 0.f;
      float x0m = (v0 && pm) ? r0[p - 1] : 0.f;
      float x0c = v0 ? r0[p] : 0.f;
      float x0p = (v0 && pp) ? r0[p + 1] : 0.f;
      const float* wb = w + (size_t)(half * 32 + ci) * 256;  // ci_glob*16*16
#pragma unroll
      for (int co = 0; co < 16; co++) {
        float4 wv1 = *(const float4*)(wb + co * 16 + ky1 * 4);
        float4 wv0 = *(const float4*)(wb + co * 16 + ky0 * 4);
        accA[co] += x1c * wv1.y + x1m * wv1.w + x0c * wv0.y + x0m * wv0.w;
        accB[co] += x1p * wv1.x + x1c * wv1.z + x0p * wv0.x + x0c * wv0.z;
      }
    }
  }
  size_t base = (size_t)img * 589824 + (size_t)oy * 192 + 2 * p;  // 16*36864
#pragma unroll
  for (int co = 0; co < 16; co++) {
    float2 v; v.x = fmaxf(accA[co], 0.f); v.y = fmaxf(accB[co], 0.f);
    *(float2*)(out + base + (size_t)co * 36864) = v;
  }
}

// ---------------- convT d1 (dual src) + sigmoid-threshold -> parent init ----------------
__global__ __launch_bounds__(256) void k_convt_d1(
    const float* __restrict__ d2, const float* __restrict__ e1,
    const float* __restrict__ w, const float* __restrict__ bias,
    int* __restrict__ parent)
{
  int idx = blockIdx.x * 256 + threadIdx.x;           // 32*384*192
  int p = idx % 192; int t = idx / 192; int oy = t % 384; int img = t / 384;
  int iy1 = (oy + 1) >> 1; int iy0 = iy1 - 1;
  int ky1 = (oy + 1) - 2 * iy1; int ky0 = ky1 + 2;
  bool v1 = (iy1 < 192), v0 = (iy0 >= 0);
  bool pm = (p > 0), pp = (p < 191);
  float zA = bias[0], zB = bias[0];
  for (int half = 0; half < 2; half++) {
    const float* src = (half == 0) ? d2 : e1;
#pragma unroll 1
    for (int ci = 0; ci < 16; ci++) {
      const float* xc = src + (size_t)img * 589824 + (size_t)ci * 36864;
      const float* r1 = xc + iy1 * 192; const float* r0 = xc + iy0 * 192;
      float x1m = (v1 && pm) ? r1[p - 1] : 0.f;
      float x1c = v1 ? r1[p] : 0.f;
      float x1p = (v1 && pp) ? r1[p + 1] : 0.f;
      float x0m = (v0 && pm) ? r0[p - 1] : 0.f;
      float x0c = v0 ? r0[p] : 0.f;
      float x0p = (v0 && pp) ? r0[p + 1] : 0.f;
      const float* wb = w + (size_t)(half * 16 + ci) * 16;   // (32,1,4,4)
      float4 wv1 = *(const float4*)(wb + ky1 * 4);
      float4 wv0 = *(const float4*)(wb + ky0 * 4);
      zA += x1c * wv1.y + x1m * wv1.w + x0c * wv0.y + x0m * wv0.w;
      zB += x1p * wv1.x + x1c * wv1.z + x0p * wv0.x + x0c * wv0.z;
    }
  }
  // sigmoid(z) > 0.75  <=>  z > ln(3)
  const float LN3 = 1.0986122886681098f;
  int* P = parent + (size_t)img * SENTI;
  int pixA = oy * 384 + 2 * p;
  P[pixA]     = (zA > LN3) ? pixA : SENTI;
  P[pixA + 1] = (zB > LN3) ? (pixA + 1) : SENTI;
}

// ---------------- tile-local CCL: 32x32 tiles, union-find in LDS ----------------
__global__ __launch_bounds__(256) void k_tile_uf(int* __restrict__ parent)
{
  __shared__ int lab[1024];
  int img = blockIdx.y;
  int tile = blockIdx.x;                              // 0..143
  int tx = tile % 12, ty = tile / 12;
  int tid = threadIdx.x;
  int* P = parent + (size_t)img * SENTI;
  int gbase = (ty * 32) * 384 + tx * 32;
  bool fg[4];
#pragma unroll
  for (int s = 0; s < 4; s++) {
    int c = tid + s * 256;
    int ly = c >> 5, lx = c & 31;
    int v = P[gbase + ly * 384 + lx];
    fg[s] = (v < SENTI);
    lab[c] = fg[s] ? c : LBG;
  }
  __syncthreads();
#pragma unroll
  for (int s = 0; s < 4; s++) {
    int c = tid + s * 256;
    if (!fg[s]) continue;
    int ly = c >> 5, lx = c & 31;
    if (lx > 0              && l_load(lab, c - 1)  != LBG) l_union(lab, c, c - 1);
    if (ly > 0) {
      if (                     l_load(lab, c - 32) != LBG) l_union(lab, c, c - 32);
      if (lx > 0            && l_load(lab, c - 33) != LBG) l_union(lab, c, c - 33);
      if (lx < 31           && l_load(lab, c - 31) != LBG) l_union(lab, c, c - 31);
    }
  }
  __syncthreads();
#pragma unroll
  for (int s = 0; s < 4; s++) {
    int c = tid + s * 256;
    if (!fg[s]) continue;
    int rc = c, q = lab[rc];
    while (q != rc) { rc = q; q = lab[rc]; }          // structure frozen after barrier
    int rly = rc >> 5, rlx = rc & 31;
    int ly = c >> 5, lx = c & 31;
    P[gbase + ly * 384 + lx] = gbase + rly * 384 + rlx;
  }
}

// ---------------- border merge: unions only across 32-aligned tile edges ----------------
__global__ __launch_bounds__(256) void k_border(int* __restrict__ parent)
{
  int idx = blockIdx.x * 256 + threadIdx.x;           // 32*147456
  int img = idx / SENTI; int p = idx - img * SENTI;
  int* P = parent + (size_t)img * SENTI;
  int x = p % 384; int y = p / 384;
  bool bx = ((x & 31) == 0) && x > 0;
  bool by = ((y & 31) == 0) && y > 0;
  if (!bx && !by) return;
  if (P[p] >= SENTI) return;
  if (bx) {
    if (            P[p - 1]   < SENTI) uf_union(P, p, p - 1);
    if (y > 0   &&  P[p - 385] < SENTI) uf_union(P, p, p - 385);
    if (y < 383 &&  P[p + 383] < SENTI) uf_union(P, p, p + 383);
  }
  if (by) {
    if (            P[p - 384] < SENTI) uf_union(P, p, p - 384);
    if (x > 0   &&  P[p - 385] < SENTI) uf_union(P, p, p - 385);
    if (x < 383 &&  P[p - 383] < SENTI) uf_union(P, p, p - 383);
  }
}

// ---------------- flatten + per-block root aggregation (one global atomic per block) ----------------
__global__ __launch_bounds__(256) void k_flatten(
    int* __restrict__ parent, int* __restrict__ rootCnt,
    int* __restrict__ rootList, int base)
{
  __shared__ int lcnt;
  __shared__ int lbase;
  __shared__ int llist[256];
  int tid = threadIdx.x;
  if (tid == 0) lcnt = 0;
  __syncthreads();
  int idx = blockIdx.x * 256 + tid;
  int img = idx / SENTI; int p = idx - img * SENTI;   // 576 blocks per image (exact)
  int* P = parent + (size_t)img * SENTI;
  int v = P[p];
  if (v < SENTI) {
    int r = v, q = P[r];
    while (q != r) { r = q; q = P[r]; }               // labels strictly decrease -> terminates
    P[p] = r;
    if (r == p) {
      int s = atomicAdd(&lcnt, 1);                    // LDS atomic: cheap, intra-CU
      llist[s] = p;
    }
  }
  __syncthreads();
  int n = lcnt;
  if (n > 0) {
    if (tid == 0) lbase = atomicAdd(&rootCnt[base + img], n);   // ONE global RMW per block
    __syncthreads();
    if (tid < n) rootList[(size_t)img * CAPR + lbase + tid] = llist[tid];  // coalesced
  }
}

// ---------------- select K smallest roots per image ----------------
__global__ __launch_bounds__(256) void k_select(
    const int* __restrict__ rootCnt, const int* __restrict__ rootList,
    int* __restrict__ U, int* __restrict__ NC, int base)
{
  int img = blockIdx.x; int tid = threadIdx.x;
  __shared__ int sv[256];
  int m = rootCnt[base + img]; if (m > CAPR) m = CAPR;
  const int* rl = rootList + (size_t)img * CAPR;
  int prev = -1;
  for (int k = 0; k < 16; k++) {
    int best = SENTI;
    for (int i = tid; i < m; i += 256) {
      int v = rl[i];
      if (v > prev && v < best) best = v;
    }
    sv[tid] = best; __syncthreads();
    for (int s = 128; s > 0; s >>= 1) {
      if (tid < s) sv[tid] = min(sv[tid], sv[tid + s]);
      __syncthreads();
    }
    int sel = sv[0];
    if (tid == 0) U[(base + img) * 16 + k] = sel;
    prev = (sel < SENTI) ? sel : 0x7FFF0000;          // once exhausted, stay SENT
    __syncthreads();
  }
  if (tid == 0) NC[base + img] = (m < 16) ? m : 16;
}

// ---------------- per-component centroid stats ----------------
__global__ __launch_bounds__(256) void k_stats(
    const int* __restrict__ parent, const int* __restrict__ U,
    int* __restrict__ CNT, float* __restrict__ SX, float* __restrict__ SY, int base)
{
  __shared__ int lc[16]; __shared__ float lx[16], ly[16];
  int tid = threadIdx.x;
  if (tid < 16) { lc[tid] = 0; lx[tid] = 0.f; ly[tid] = 0.f; }
  __syncthreads();
  int img = blockIdx.y; int g = base + img;
  int p = blockIdx.x * 256 + tid;                     // 576*256 = 147456
  int lbl = parent[(size_t)img * SENTI + p];
  if (lbl < SENTI) {
    const int* u = U + g * 16;
    int slot = -1;
#pragma unroll
    for (int s = 0; s < 16; s++) if (u[s] == lbl) slot = s;
    if (slot >= 0) {
      atomicAdd(&lc[slot], 1);
      atomicAdd(&lx[slot], (float)(p % 384));
      atomicAdd(&ly[slot], (float)(p / 384));
    }
  }
  __syncthreads();
  if (tid < 16 && lc[tid] > 0) {
    atomicAdd(&CNT[g * 16 + tid], lc[tid]);
    atomicAdd(&SX[g * 16 + tid], lx[tid]);
    atomicAdd(&SY[g * 16 + tid], ly[tid]);
  }
}

// ---------------- polar sort + greedy match + MLP ----------------
__global__ __launch_bounds__(64) void k_final(
    const int* __restrict__ U, const int* __restrict__ NC,
    const int* __restrict__ CNT, const float* __restrict__ SX,
    const float* __restrict__ SY,
    const float* __restrict__ w1, const float* __restrict__ b1,
    const float* __restrict__ w2, const float* __restrict__ b2,
    const float* __restrict__ w3, const float* __restrict__ b3,
    float* __restrict__ out)
{
  int b = threadIdx.x;
  if (b >= 32) return;
  const float INF = __builtin_inff();
  float R[2][16], A[2][16]; int N[2];
  for (int side = 0; side < 2; side++) {
    int img = b + side * 32;
    float rr[16], aa[16], key[16];
    for (int s = 0; s < 16; s++) {
      bool valid = U[img * 16 + s] < SENTI;
      float c = fmaxf((float)CNT[img * 16 + s], 1.f);
      float cx = SX[img * 16 + s] / c, cy = SY[img * 16 + s] / c;
      float dx = cx - 192.f, dy = cy - 192.f;
      rr[s] = sqrtf(dx * dx + dy * dy);
      float ang = atan2f(dy, dx) * 57.29577951308232f;   // rad2deg
      ang = fmodf(ang, 360.f);
      if (ang < 0.f) ang += 360.f;                       // python % semantics
      aa[s] = ang;
      key[s] = valid ? rr[s] : INF;
    }
    bool taken[16];
    for (int s = 0; s < 16; s++) taken[s] = false;
    for (int k = 0; k < 16; k++) {                       // stable selection sort by (key, idx)
      int bi = -1; float bk = 0.f;
      for (int s = 0; s < 16; s++) {
        if (taken[s]) continue;
        if (bi < 0 || key[s] < bk) { bi = s; bk = key[s]; }
      }
      taken[bi] = true;
      bool val = (key[bi] < INF);
      R[side][k] = val ? rr[bi] : 0.f;
      A[side][k] = val ? aa[bi] : 0.f;
    }
    N[side] = NC[img];
  }
  // greedy nearest-radius matching (A = smaller-or-equal set)
  int n1 = N[0], n2 = N[1];
  bool sw = n1 > n2;
  float* rA = sw ? R[1] : R[0];
  float* aA = sw ? A[1] : A[0];
  float* rB = sw ? R[0] : R[1];
  float* aB = sw ? A[0] : A[1];
  int nA = sw ? n2 : n1;
  int nB = sw ? n1 : n2;
  bool used[16];
  for (int s = 0; s < 16; s++) used[s] = false;
  float f[32];
  for (int i = 0; i < 16; i++) {
    bool vi = i < nA;
    float best = 0.f; int j = 0; bool found = false;
    for (int jj = 0; jj < 16; jj++) {
      if (used[jj] || jj >= nB) continue;
      float d = fabsf(rB[jj] - rA[i]);
      if (!found || d < best) { best = d; j = jj; found = true; }
    }
    float dr = rA[i] - rB[j];
    float da = fabsf(sinf((aA[i] - aB[j]) * 0.017453292519943295f));  // deg2rad
    f[2 * i]     = vi ? dr : 0.f;
    f[2 * i + 1] = vi ? da : 0.f;
    if (vi) used[j] = true;
  }
  // MLP 32 -> 32 -> 8 -> 1
  float h1[32];
  for (int jj = 0; jj < 32; jj++) {
    float s = b1[jj];
    for (int k2 = 0; k2 < 32; k2++) s += w1[jj * 32 + k2] * f[k2];
    h1[jj] = fmaxf(s, 0.f);
  }
  float h2[8];
  for (int jj = 0; jj < 8; jj++) {
    float s = b2[jj];
    for (int k2 = 0; k2 < 32; k2++) s += w2[jj * 32 + k2] * h1[k2];
    h2[jj] = fmaxf(s, 0.f);
  }
  float o = b3[0];
  for (int k2 = 0; k2 < 8; k2++) o += w3[k2] * h2[k2];
  out[b] = o;
}

// ---------------- host ----------------
extern "C" void kernel_launch(void* const* d_in, const int* in_sizes, int n_in,
                              void* d_out, int out_size, void* d_ws, size_t ws_size,
                              hipStream_t stream)
{
  (void)in_sizes; (void)n_in; (void)out_size; (void)ws_size;
  const float* x1  = (const float*)d_in[0];
  const float* x2  = (const float*)d_in[1];
  const float* e1w = (const float*)d_in[2];  const float* e1b = (const float*)d_in[3];
  const float* e2w = (const float*)d_in[4];  const float* e2b = (const float*)d_in[5];
  const float* e3w = (const float*)d_in[6];  const float* e3b = (const float*)d_in[7];
  const float* d3w = (const float*)d_in[8];  const float* d3b = (const float*)d_in[9];
  const float* d2w = (const float*)d_in[10]; const float* d2b = (const float*)d_in[11];
  const float* d1w = (const float*)d_in[12]; const float* d1b = (const float*)d_in[13];
  const float* w1  = (const float*)d_in[14]; const float* b1  = (const float*)d_in[15];
  const float* w2  = (const float*)d_in[16]; const float* b2  = (const float*)d_in[17];
  const float* w3  = (const float*)d_in[18]; const float* b3  = (const float*)d_in[19];

  // workspace layout (two half-batch passes; peak ~245.4 MB)
  char* ws = (char*)d_ws;
  float* E1 = (float*)(ws + 0);                       //  75,497,472 B (32,16,192,192)
  float* E2 = (float*)(ws + 75497472);                //  37,748,736 B (32,32,96,96)
  float* E3 = (float*)(ws + 113246208);               //  18,874,368 B (32,64,48,48)
  float* D3 = (float*)(ws + 132120576);               //  37,748,736 B (32,32,96,96)
  float* D2 = (float*)(ws + 169869312);               //  75,497,472 B (32,16,192,192)
  char* small = ws + 245366784;
  int* PARENT = (int*)E3;                             // alias: E3 dead after d3
  int* ROOTL  = (int*)E2;                             // alias: E2 dead after d2
  int*   ROOTC = (int*)(small);                       // 64 ints
  int*   U     = (int*)(small + 256);                 // 64*16 ints
  int*   NC    = (int*)(small + 4352);                // 64 ints
  int*   CNT   = (int*)(small + 4608);                // 64*16 ints
  float* SX    = (float*)(small + 8704);              // 64*16 f
  float* SY    = (float*)(small + 12800);             // 64*16 f

  hipMemsetAsync(ROOTC, 0, 256, stream);
  hipMemsetAsync(CNT, 0, 4096, stream);
  hipMemsetAsync(SX, 0, 4096, stream);
  hipMemsetAsync(SY, 0, 4096, stream);

  for (int pass = 0; pass < 2; pass++) {
    const float* x = (pass == 0) ? x1 : x2;
    int base = pass * 32;
    k_conv_e1<<<4608, 256, 0, stream>>>(x, e1w, e1b, E1);
    k_conv_e2<<<576, 256, 0, stream>>>(E1, e2w, e2b, E2);
    k_conv_e3<<<dim3(144, 2), 256, 0, stream>>>(E2, e3w, e3b, E3);
    k_convt_d3<<<576, 256, 0, stream>>>(E3, d3w, d3b, D3);
    k_convt_d2<<<2304, 256, 0, stream>>>(D3, E2, d2w, d2b, D2);
    k_convt_d1<<<9216, 256, 0, stream>>>(D2, E1, d1w, d1b, PARENT);
    k_tile_uf<<<dim3(144, 32), 256, 0, stream>>>(PARENT);
    k_border<<<18432, 256, 0, stream>>>(PARENT);
    k_flatten<<<18432, 256, 0, stream>>>(PARENT, ROOTC, ROOTL, base);
    k_select<<<32, 256, 0, stream>>>(ROOTC, ROOTL, U, NC, base);
    k_stats<<<dim3(576, 32), 256, 0, stream>>>(PARENT, U, CNT, SX, SY, base);
  }
  k_final<<<1, 64, 0, stream>>>(U, NC, CNT, SX, SY, w1, b1, w2, b2, w3, b3, (float*)d_out);
}

// Round 4
// 3754.256 us; speedup vs baseline: 3.5110x; 1.1099x over previous
//
#include <hip/hip_runtime.h>
#include <math.h>

// ---------------- problem constants ----------------
#define NIMG 32          // images per pass (x1 pass, x2 pass)
#define SENTI 147456     // H*W sentinel
#define CAPR 36864       // max 8-connected components in 384x384
#define LBG 0x7FFFFFFF   // LDS background marker

// ---------------- global union-find (device-scope safe, used on borders only) ----------------
__device__ __forceinline__ int uf_load(int* P, int i) {
  return __hip_atomic_load(&P[i], __ATOMIC_RELAXED, __HIP_MEMORY_SCOPE_AGENT);
}
__device__ int uf_find(int* P, int i) {
  int p = uf_load(P, i);
  while (p != i) {
    int gp = uf_load(P, p);
    if (gp != p) atomicMin(&P[i], gp);   // path halving, monotone decreasing => safe
    i = p; p = gp;
  }
  return i;
}
__device__ void uf_union(int* P, int a, int b) {
  while (true) {
    a = uf_find(P, a); b = uf_find(P, b);
    if (a == b) return;
    if (a > b) { int t = a; a = b; b = t; }   // a < b : attach b under a (min root wins)
    int old = atomicMin(&P[b], a);
    if (old == b) return;
    b = old;
  }
}

// ---------------- LDS union-find (tile-local) ----------------
__device__ __forceinline__ int l_load(int* lab, int i) {
  return __hip_atomic_load(&lab[i], __ATOMIC_RELAXED, __HIP_MEMORY_SCOPE_WORKGROUP);
}
__device__ int l_find(int* lab, int i) {
  int p = l_load(lab, i);
  while (p != i) { int gp = l_load(lab, p); i = p; p = gp; }
  return i;
}
__device__ void l_union(int* lab, int a, int b) {
  while (true) {
    a = l_find(lab, a); b = l_find(lab, b);
    if (a == b) return;
    if (a > b) { int t = a; a = b; b = t; }
    int old = atomicMin(&lab[b], a);
    if (old == b) return;
    b = old;
  }
}

// ---------------- conv e1: (32,1,384,384) -> (32,16,192,192), k4 s2 p1 + relu ----------------
__global__ __launch_bounds__(256) void k_conv_e1(
    const float* __restrict__ x, const float* __restrict__ w,
    const float* __restrict__ bias, float* __restrict__ out)
{
  int idx = blockIdx.x * 256 + threadIdx.x;           // 32*192*192
  int ox = idx % 192; int t = idx / 192; int oy = t % 192; int img = t / 192;
  const float* xi = x + (size_t)img * 147456;
  float acc[16];
#pragma unroll
  for (int c = 0; c < 16; c++) acc[c] = bias[c];
#pragma unroll
  for (int ky = 0; ky < 4; ky++) {
    int iy = 2 * oy + ky - 1;
    if (iy < 0 || iy >= 384) continue;
    const float* row = xi + iy * 384;
#pragma unroll
    for (int kx = 0; kx < 4; kx++) {
      int ix = 2 * ox + kx - 1;
      if (ix < 0 || ix >= 384) continue;
      float v = row[ix];
#pragma unroll
      for (int c = 0; c < 16; c++) acc[c] = fmaf(v, w[c * 16 + ky * 4 + kx], acc[c]);
    }
  }
  size_t base = (size_t)img * 589824 + (size_t)oy * 192 + ox;   // 16*36864
#pragma unroll
  for (int c = 0; c < 16; c++) out[base + (size_t)c * 36864] = fmaxf(acc[c], 0.f);
}

// ---------------- conv e2: (32,16,192,192) -> (32,32,96,96) ----------------
__global__ __launch_bounds__(256) void k_conv_e2(
    const float* __restrict__ in, const float* __restrict__ w,
    const float* __restrict__ bias, float* __restrict__ out)
{
  int idx = blockIdx.x * 256 + threadIdx.x;           // 32*96*48 (2 cols/thread)
  int p = idx % 48; int t = idx / 48; int oy = t % 96; int img = t / 96;
  const float* xin = in + (size_t)img * 589824;
  float accA[32], accB[32];
#pragma unroll
  for (int c = 0; c < 32; c++) { float bv = bias[c]; accA[c] = bv; accB[c] = bv; }
#pragma unroll 1
  for (int ci = 0; ci < 16; ci++) {
    const float* xc = xin + (size_t)ci * 36864;
#pragma unroll
    for (int ky = 0; ky < 4; ky++) {
      int iy = 2 * oy + ky - 1;
      float xv[6];
      if (iy >= 0 && iy < 192) {
        const float* row = xc + iy * 192;
        int c0 = 4 * p - 1;
#pragma unroll
        for (int u = 0; u < 6; u++) {
          int ix = c0 + u;
          xv[u] = (ix >= 0 && ix < 192) ? row[ix] : 0.f;
        }
      } else {
#pragma unroll
        for (int u = 0; u < 6; u++) xv[u] = 0.f;
      }
#pragma unroll
      for (int co = 0; co < 32; co++) {
        float4 wv = *(const float4*)(w + ((size_t)co * 16 + ci) * 16 + ky * 4);
        accA[co] = fmaf(xv[3], wv.w, fmaf(xv[2], wv.z, fmaf(xv[1], wv.y, fmaf(xv[0], wv.x, accA[co]))));
        accB[co] = fmaf(xv[5], wv.w, fmaf(xv[4], wv.z, fmaf(xv[3], wv.y, fmaf(xv[2], wv.x, accB[co]))));
      }
    }
  }
  size_t base = (size_t)img * 294912 + (size_t)oy * 96 + 2 * p;  // 32*9216
#pragma unroll
  for (int co = 0; co < 32; co++) {
    float2 v; v.x = fmaxf(accA[co], 0.f); v.y = fmaxf(accB[co], 0.f);
    *(float2*)(out + base + (size_t)co * 9216) = v;
  }
}

// ---------------- conv e3: (32,32,96,96) -> (32,64,48,48), co split in 2 groups ----------------
__global__ __launch_bounds__(256) void k_conv_e3(
    const float* __restrict__ in, const float* __restrict__ w,
    const float* __restrict__ bias, float* __restrict__ out)
{
  int idx = blockIdx.x * 256 + threadIdx.x;           // 32*48*24
  int cog = blockIdx.y;                               // 0/1 -> co groups of 32
  int p = idx % 24; int t = idx / 24; int oy = t % 48; int img = t / 48;
  const float* xin = in + (size_t)img * 294912;
  float accA[32], accB[32];
#pragma unroll
  for (int c = 0; c < 32; c++) { float bv = bias[cog * 32 + c]; accA[c] = bv; accB[c] = bv; }
#pragma unroll 1
  for (int ci = 0; ci < 32; ci++) {
    const float* xc = xin + (size_t)ci * 9216;
#pragma unroll
    for (int ky = 0; ky < 4; ky++) {
      int iy = 2 * oy + ky - 1;
      float xv[6];
      if (iy >= 0 && iy < 96) {
        const float* row = xc + iy * 96;
        int c0 = 4 * p - 1;
#pragma unroll
        for (int u = 0; u < 6; u++) {
          int ix = c0 + u;
          xv[u] = (ix >= 0 && ix < 96) ? row[ix] : 0.f;
        }
      } else {
#pragma unroll
        for (int u = 0; u < 6; u++) xv[u] = 0.f;
      }
#pragma unroll
      for (int co = 0; co < 32; co++) {
        float4 wv = *(const float4*)(w + ((size_t)(cog * 32 + co) * 32 + ci) * 16 + ky * 4);
        accA[co] = fmaf(xv[3], wv.w, fmaf(xv[2], wv.z, fmaf(xv[1], wv.y, fmaf(xv[0], wv.x, accA[co]))));
        accB[co] = fmaf(xv[5], wv.w, fmaf(xv[4], wv.z, fmaf(xv[3], wv.y, fmaf(xv[2], wv.x, accB[co]))));
      }
    }
  }
  size_t base = (size_t)img * 147456 + (size_t)(cog * 32) * 2304 + (size_t)oy * 48 + 2 * p;
#pragma unroll
  for (int co = 0; co < 32; co++) {
    float2 v; v.x = fmaxf(accA[co], 0.f); v.y = fmaxf(accB[co], 0.f);
    *(float2*)(out + base + (size_t)co * 2304) = v;
  }
}

// ---------------- convT d3: (32,64,48,48) -> (32,32,96,96), w (64,32,4,4) ----------------
__global__ __launch_bounds__(256) void k_convt_d3(
    const float* __restrict__ in, const float* __restrict__ w,
    const float* __restrict__ bias, float* __restrict__ out)
{
  int idx = blockIdx.x * 256 + threadIdx.x;           // 32*96*48
  int p = idx % 48; int t = idx / 48; int oy = t % 96; int img = t / 96;
  int iy1 = (oy + 1) >> 1; int iy0 = iy1 - 1;
  int ky1 = (oy + 1) - 2 * iy1; int ky0 = ky1 + 2;    // ky1 in {0,1}
  bool v1 = (iy1 < 48), v0 = (iy0 >= 0);
  bool pm = (p > 0), pp = (p < 47);
  float accA[32], accB[32];
#pragma unroll
  for (int c = 0; c < 32; c++) { float bv = bias[c]; accA[c] = bv; accB[c] = bv; }
#pragma unroll 1
  for (int ci = 0; ci < 64; ci++) {
    const float* xc = in + (size_t)img * 147456 + (size_t)ci * 2304;
    const float* r1 = xc + iy1 * 48; const float* r0 = xc + iy0 * 48;
    float x1m = (v1 && pm) ? r1[p - 1] : 0.f;
    float x1c = v1 ? r1[p] : 0.f;
    float x1p = (v1 && pp) ? r1[p + 1] : 0.f;
    float x0m = (v0 && pm) ? r0[p - 1] : 0.f;
    float x0c = v0 ? r0[p] : 0.f;
    float x0p = (v0 && pp) ? r0[p + 1] : 0.f;
    const float* wb = w + (size_t)ci * 512;           // ci*32*16
#pragma unroll
    for (int co = 0; co < 32; co++) {
      float4 wv1 = *(const float4*)(wb + co * 16 + ky1 * 4);
      float4 wv0 = *(const float4*)(wb + co * 16 + ky0 * 4);
      accA[co] += x1c * wv1.y + x1m * wv1.w + x0c * wv0.y + x0m * wv0.w;
      accB[co] += x1p * wv1.x + x1c * wv1.z + x0p * wv0.x + x0c * wv0.z;
    }
  }
  size_t base = (size_t)img * 294912 + (size_t)oy * 96 + 2 * p;
#pragma unroll
  for (int co = 0; co < 32; co++) {
    float2 v; v.x = fmaxf(accA[co], 0.f); v.y = fmaxf(accB[co], 0.f);
    *(float2*)(out + base + (size_t)co * 9216) = v;
  }
}

// ---------------- convT d2 (dual src): [D3 | E2] (32,64,96,96) -> (32,16,192,192), w (64,16,4,4) ----------------
// 8 output cols per thread (4 pairs): amortizes weight loads 4x vs 2-col version.
__global__ __launch_bounds__(256) void k_convt_d2(
    const float* __restrict__ d3, const float* __restrict__ e2,
    const float* __restrict__ w, const float* __restrict__ bias,
    float* __restrict__ out)
{
  int idx = blockIdx.x * 256 + threadIdx.x;           // 32*192*24
  int pg = idx % 24; int t = idx / 24; int oy = t % 192; int img = t / 192;
  int iy1 = (oy + 1) >> 1; int iy0 = iy1 - 1;
  int ky1 = (oy + 1) - 2 * iy1; int ky0 = ky1 + 2;    // ky1 in {0,1}
  bool v1 = (iy1 < 96), v0 = (iy0 >= 0);
  int c0 = 4 * pg - 1;                                // input col base (6 cols used)
  float acc[16][8];
#pragma unroll
  for (int co = 0; co < 16; co++) {
    float bv = bias[co];
#pragma unroll
    for (int j = 0; j < 8; j++) acc[co][j] = bv;
  }
  for (int half = 0; half < 2; half++) {
    const float* src = (half == 0) ? d3 : e2;
#pragma unroll 1
    for (int ci = 0; ci < 32; ci++) {
      const float* xc = src + (size_t)img * 294912 + (size_t)ci * 9216;
      const float* r1 = xc + iy1 * 96; const float* r0 = xc + iy0 * 96;
      float x1[6], x0[6];
#pragma unroll
      for (int u = 0; u < 6; u++) {
        int ix = c0 + u;
        bool cb = (ix >= 0) && (ix < 96);
        x1[u] = (v1 && cb) ? r1[ix] : 0.f;
        x0[u] = (v0 && cb) ? r0[ix] : 0.f;
      }
      const float* wb = w + (size_t)(half * 32 + ci) * 256;  // ci_glob*16*16
#pragma unroll
      for (int co = 0; co < 16; co++) {
        float4 wv1 = *(const float4*)(wb + co * 16 + ky1 * 4);
        float4 wv0 = *(const float4*)(wb + co * 16 + ky0 * 4);
#pragma unroll
        for (int j = 0; j < 4; j++) {                 // output pair j -> cols 8*pg+2j, +1
          acc[co][2 * j]     += x1[j + 1] * wv1.y + x1[j] * wv1.w
                              + x0[j + 1] * wv0.y + x0[j] * wv0.w;
          acc[co][2 * j + 1] += x1[j + 2] * wv1.x + x1[j + 1] * wv1.z
                              + x0[j + 2] * wv0.x + x0[j + 1] * wv0.z;
        }
      }
    }
  }
  size_t base = (size_t)img * 589824 + (size_t)oy * 192 + 8 * pg;  // 16*36864
#pragma unroll
  for (int co = 0; co < 16; co++) {
    float4 a, b;
    a.x = fmaxf(acc[co][0], 0.f); a.y = fmaxf(acc[co][1], 0.f);
    a.z = fmaxf(acc[co][2], 0.f); a.w = fmaxf(acc[co][3], 0.f);
    b.x = fmaxf(acc[co][4], 0.f); b.y = fmaxf(acc[co][5], 0.f);
    b.z = fmaxf(acc[co][6], 0.f); b.w = fmaxf(acc[co][7], 0.f);
    *(float4*)(out + base + (size_t)co * 36864)     = a;
    *(float4*)(out + base + (size_t)co * 36864 + 4) = b;
  }
}

// ---------------- convT d1 (dual src) + sigmoid-threshold -> parent init ----------------
__global__ __launch_bounds__(256) void k_convt_d1(
    const float* __restrict__ d2, const float* __restrict__ e1,
    const float* __restrict__ w, const float* __restrict__ bias,
    int* __restrict__ parent)
{
  int idx = blockIdx.x * 256 + threadIdx.x;           // 32*384*192
  int p = idx % 192; int t = idx / 192; int oy = t % 384; int img = t / 384;
  int iy1 = (oy + 1) >> 1; int iy0 = iy1 - 1;
  int ky1 = (oy + 1) - 2 * iy1; int ky0 = ky1 + 2;
  bool v1 = (iy1 < 192), v0 = (iy0 >= 0);
  bool pm = (p > 0), pp = (p < 191);
  float zA = bias[0], zB = bias[0];
  for (int half = 0; half < 2; half++) {
    const float* src = (half == 0) ? d2 : e1;
#pragma unroll 1
    for (int ci = 0; ci < 16; ci++) {
      const float* xc = src + (size_t)img * 589824 + (size_t)ci * 36864;
      const float* r1 = xc + iy1 * 192; const float* r0 = xc + iy0 * 192;
      float x1m = (v1 && pm) ? r1[p - 1] : 0.f;
      float x1c = v1 ? r1[p] : 0.f;
      float x1p = (v1 && pp) ? r1[p + 1] : 0.f;
      float x0m = (v0 && pm) ? r0[p - 1] : 0.f;
      float x0c = v0 ? r0[p] : 0.f;
      float x0p = (v0 && pp) ? r0[p + 1] : 0.f;
      const float* wb = w + (size_t)(half * 16 + ci) * 16;   // (32,1,4,4)
      float4 wv1 = *(const float4*)(wb + ky1 * 4);
      float4 wv0 = *(const float4*)(wb + ky0 * 4);
      zA += x1c * wv1.y + x1m * wv1.w + x0c * wv0.y + x0m * wv0.w;
      zB += x1p * wv1.x + x1c * wv1.z + x0p * wv0.x + x0c * wv0.z;
    }
  }
  // sigmoid(z) > 0.75  <=>  z > ln(3)
  const float LN3 = 1.0986122886681098f;
  int* P = parent + (size_t)img * SENTI;
  int pixA = oy * 384 + 2 * p;
  P[pixA]     = (zA > LN3) ? pixA : SENTI;
  P[pixA + 1] = (zB > LN3) ? (pixA + 1) : SENTI;
}

// ---------------- tile-local CCL: 32x32 tiles, union-find in LDS ----------------
__global__ __launch_bounds__(256) void k_tile_uf(int* __restrict__ parent)
{
  __shared__ int lab[1024];
  int img = blockIdx.y;
  int tile = blockIdx.x;                              // 0..143
  int tx = tile % 12, ty = tile / 12;
  int tid = threadIdx.x;
  int* P = parent + (size_t)img * SENTI;
  int gbase = (ty * 32) * 384 + tx * 32;
  bool fg[4];
#pragma unroll
  for (int s = 0; s < 4; s++) {
    int c = tid + s * 256;
    int ly = c >> 5, lx = c & 31;
    int v = P[gbase + ly * 384 + lx];
    fg[s] = (v < SENTI);
    lab[c] = fg[s] ? c : LBG;
  }
  __syncthreads();
#pragma unroll
  for (int s = 0; s < 4; s++) {
    int c = tid + s * 256;
    if (!fg[s]) continue;
    int ly = c >> 5, lx = c & 31;
    if (lx > 0              && l_load(lab, c - 1)  != LBG) l_union(lab, c, c - 1);
    if (ly > 0) {
      if (                     l_load(lab, c - 32) != LBG) l_union(lab, c, c - 32);
      if (lx > 0            && l_load(lab, c - 33) != LBG) l_union(lab, c, c - 33);
      if (lx < 31           && l_load(lab, c - 31) != LBG) l_union(lab, c, c - 31);
    }
  }
  __syncthreads();
#pragma unroll
  for (int s = 0; s < 4; s++) {
    int c = tid + s * 256;
    if (!fg[s]) continue;
    int rc = c, q = lab[rc];
    while (q != rc) { rc = q; q = lab[rc]; }          // structure frozen after barrier
    int rly = rc >> 5, rlx = rc & 31;
    int ly = c >> 5, lx = c & 31;
    P[gbase + ly * 384 + lx] = gbase + rly * 384 + rlx;
  }
}

// ---------------- border merge: unions only across 32-aligned tile edges ----------------
__global__ __launch_bounds__(256) void k_border(int* __restrict__ parent)
{
  int idx = blockIdx.x * 256 + threadIdx.x;           // 32*147456
  int img = idx / SENTI; int p = idx - img * SENTI;
  int* P = parent + (size_t)img * SENTI;
  int x = p % 384; int y = p / 384;
  bool bx = ((x & 31) == 0) && x > 0;
  bool by = ((y & 31) == 0) && y > 0;
  if (!bx && !by) return;
  if (P[p] >= SENTI) return;
  if (bx) {
    if (            P[p - 1]   < SENTI) uf_union(P, p, p - 1);
    if (y > 0   &&  P[p - 385] < SENTI) uf_union(P, p, p - 385);
    if (y < 383 &&  P[p + 383] < SENTI) uf_union(P, p, p + 383);
  }
  if (by) {
    if (            P[p - 384] < SENTI) uf_union(P, p, p - 384);
    if (x > 0   &&  P[p - 385] < SENTI) uf_union(P, p, p - 385);
    if (x < 383 &&  P[p - 383] < SENTI) uf_union(P, p, p - 383);
  }
}

// ---------------- flatten + per-block root aggregation (one global atomic per block) ----------------
__global__ __launch_bounds__(256) void k_flatten(
    int* __restrict__ parent, int* __restrict__ rootCnt,
    int* __restrict__ rootList, int base)
{
  __shared__ int lcnt;
  __shared__ int lbase;
  __shared__ int llist[256];
  int tid = threadIdx.x;
  if (tid == 0) lcnt = 0;
  __syncthreads();
  int idx = blockIdx.x * 256 + tid;
  int img = idx / SENTI; int p = idx - img * SENTI;   // 576 blocks per image (exact)
  int* P = parent + (size_t)img * SENTI;
  int v = P[p];
  if (v < SENTI) {
    int r = v, q = P[r];
    while (q != r) { r = q; q = P[r]; }               // labels strictly decrease -> terminates
    P[p] = r;
    if (r == p) {
      int s = atomicAdd(&lcnt, 1);                    // LDS atomic: cheap, intra-CU
      llist[s] = p;
    }
  }
  __syncthreads();
  int n = lcnt;
  if (n > 0) {
    if (tid == 0) lbase = atomicAdd(&rootCnt[base + img], n);   // ONE global RMW per block
    __syncthreads();
    if (tid < n) rootList[(size_t)img * CAPR + lbase + tid] = llist[tid];  // coalesced
  }
}

// ---------------- select K smallest roots per image ----------------
__global__ __launch_bounds__(256) void k_select(
    const int* __restrict__ rootCnt, const int* __restrict__ rootList,
    int* __restrict__ U, int* __restrict__ NC, int base)
{
  int img = blockIdx.x; int tid = threadIdx.x;
  __shared__ int sv[256];
  int m = rootCnt[base + img]; if (m > CAPR) m = CAPR;
  const int* rl = rootList + (size_t)img * CAPR;
  int prev = -1;
  for (int k = 0; k < 16; k++) {
    int best = SENTI;
    for (int i = tid; i < m; i += 256) {
      int v = rl[i];
      if (v > prev && v < best) best = v;
    }
    sv[tid] = best; __syncthreads();
    for (int s = 128; s > 0; s >>= 1) {
      if (tid < s) sv[tid] = min(sv[tid], sv[tid + s]);
      __syncthreads();
    }
    int sel = sv[0];
    if (tid == 0) U[(base + img) * 16 + k] = sel;
    prev = (sel < SENTI) ? sel : 0x7FFF0000;          // once exhausted, stay SENT
    __syncthreads();
  }
  if (tid == 0) NC[base + img] = (m < 16) ? m : 16;
}

// ---------------- per-component centroid stats ----------------
__global__ __launch_bounds__(256) void k_stats(
    const int* __restrict__ parent, const int* __restrict__ U,
    int* __restrict__ CNT, float* __restrict__ SX, float* __restrict__ SY, int base)
{
  __shared__ int lc[16]; __shared__ float lx[16], ly[16];
  int tid = threadIdx.x;
  if (tid < 16) { lc[tid] = 0; lx[tid] = 0.f; ly[tid] = 0.f; }
  __syncthreads();
  int img = blockIdx.y; int g = base + img;
  int p = blockIdx.x * 256 + tid;                     // 576*256 = 147456
  int lbl = parent[(size_t)img * SENTI + p];
  if (lbl < SENTI) {
    const int* u = U + g * 16;
    int slot = -1;
#pragma unroll
    for (int s = 0; s < 16; s++) if (u[s] == lbl) slot = s;
    if (slot >= 0) {
      atomicAdd(&lc[slot], 1);
      atomicAdd(&lx[slot], (float)(p % 384));
      atomicAdd(&ly[slot], (float)(p / 384));
    }
  }
  __syncthreads();
  if (tid < 16 && lc[tid] > 0) {
    atomicAdd(&CNT[g * 16 + tid], lc[tid]);
    atomicAdd(&SX[g * 16 + tid], lx[tid]);
    atomicAdd(&SY[g * 16 + tid], ly[tid]);
  }
}

// ---------------- polar sort + greedy match + MLP ----------------
__global__ __launch_bounds__(64) void k_final(
    const int* __restrict__ U, const int* __restrict__ NC,
    const int* __restrict__ CNT, const float* __restrict__ SX,
    const float* __restrict__ SY,
    const float* __restrict__ w1, const float* __restrict__ b1,
    const float* __restrict__ w2, const float* __restrict__ b2,
    const float* __restrict__ w3, const float* __restrict__ b3,
    float* __restrict__ out)
{
  int b = threadIdx.x;
  if (b >= 32) return;
  const float INF = __builtin_inff();
  float R[2][16], A[2][16]; int N[2];
  for (int side = 0; side < 2; side++) {
    int img = b + side * 32;
    float rr[16], aa[16], key[16];
    for (int s = 0; s < 16; s++) {
      bool valid = U[img * 16 + s] < SENTI;
      float c = fmaxf((float)CNT[img * 16 + s], 1.f);
      float cx = SX[img * 16 + s] / c, cy = SY[img * 16 + s] / c;
      float dx = cx - 192.f, dy = cy - 192.f;
      rr[s] = sqrtf(dx * dx + dy * dy);
      float ang = atan2f(dy, dx) * 57.29577951308232f;   // rad2deg
      ang = fmodf(ang, 360.f);
      if (ang < 0.f) ang += 360.f;                       // python % semantics
      aa[s] = ang;
      key[s] = valid ? rr[s] : INF;
    }
    bool taken[16];
    for (int s = 0; s < 16; s++) taken[s] = false;
    for (int k = 0; k < 16; k++) {                       // stable selection sort by (key, idx)
      int bi = -1; float bk = 0.f;
      for (int s = 0; s < 16; s++) {
        if (taken[s]) continue;
        if (bi < 0 || key[s] < bk) { bi = s; bk = key[s]; }
      }
      taken[bi] = true;
      bool val = (key[bi] < INF);
      R[side][k] = val ? rr[bi] : 0.f;
      A[side][k] = val ? aa[bi] : 0.f;
    }
    N[side] = NC[img];
  }
  // greedy nearest-radius matching (A = smaller-or-equal set)
  int n1 = N[0], n2 = N[1];
  bool sw = n1 > n2;
  float* rA = sw ? R[1] : R[0];
  float* aA = sw ? A[1] : A[0];
  float* rB = sw ? R[0] : R[1];
  float* aB = sw ? A[0] : A[1];
  int nA = sw ? n2 : n1;
  int nB = sw ? n1 : n2;
  bool used[16];
  for (int s = 0; s < 16; s++) used[s] = false;
  float f[32];
  for (int i = 0; i < 16; i++) {
    bool vi = i < nA;
    float best = 0.f; int j = 0; bool found = false;
    for (int jj = 0; jj < 16; jj++) {
      if (used[jj] || jj >= nB) continue;
      float d = fabsf(rB[jj] - rA[i]);
      if (!found || d < best) { best = d; j = jj; found = true; }
    }
    float dr = rA[i] - rB[j];
    float da = fabsf(sinf((aA[i] - aB[j]) * 0.017453292519943295f));  // deg2rad
    f[2 * i]     = vi ? dr : 0.f;
    f[2 * i + 1] = vi ? da : 0.f;
    if (vi) used[j] = true;
  }
  // MLP 32 -> 32 -> 8 -> 1
  float h1[32];
  for (int jj = 0; jj < 32; jj++) {
    float s = b1[jj];
    for (int k2 = 0; k2 < 32; k2++) s += w1[jj * 32 + k2] * f[k2];
    h1[jj] = fmaxf(s, 0.f);
  }
  float h2[8];
  for (int jj = 0; jj < 8; jj++) {
    float s = b2[jj];
    for (int k2 = 0; k2 < 32; k2++) s += w2[jj * 32 + k2] * h1[k2];
    h2[jj] = fmaxf(s, 0.f);
  }
  float o = b3[0];
  for (int k2 = 0; k2 < 8; k2++) o += w3[k2] * h2[k2];
  out[b] = o;
}

// ---------------- host ----------------
extern "C" void kernel_launch(void* const* d_in, const int* in_sizes, int n_in,
                              void* d_out, int out_size, void* d_ws, size_t ws_size,
                              hipStream_t stream)
{
  (void)in_sizes; (void)n_in; (void)out_size; (void)ws_size;
  const float* x1  = (const float*)d_in[0];
  const float* x2  = (const float*)d_in[1];
  const float* e1w = (const float*)d_in[2];  const float* e1b = (const float*)d_in[3];
  const float* e2w = (const float*)d_in[4];  const float* e2b = (const float*)d_in[5];
  const float* e3w = (const float*)d_in[6];  const float* e3b = (const float*)d_in[7];
  const float* d3w = (const float*)d_in[8];  const float* d3b = (const float*)d_in[9];
  const float* d2w = (const float*)d_in[10]; const float* d2b = (const float*)d_in[11];
  const float* d1w = (const float*)d_in[12]; const float* d1b = (const float*)d_in[13];
  const float* w1  = (const float*)d_in[14]; const float* b1  = (const float*)d_in[15];
  const float* w2  = (const float*)d_in[16]; const float* b2  = (const float*)d_in[17];
  const float* w3  = (const float*)d_in[18]; const float* b3  = (const float*)d_in[19];

  // workspace layout (two half-batch passes; peak ~245.4 MB)
  char* ws = (char*)d_ws;
  float* E1 = (float*)(ws + 0);                       //  75,497,472 B (32,16,192,192)
  float* E2 = (float*)(ws + 75497472);                //  37,748,736 B (32,32,96,96)
  float* E3 = (float*)(ws + 113246208);               //  18,874,368 B (32,64,48,48)
  float* D3 = (float*)(ws + 132120576);               //  37,748,736 B (32,32,96,96)
  float* D2 = (float*)(ws + 169869312);               //  75,497,472 B (32,16,192,192)
  char* small = ws + 245366784;
  int* PARENT = (int*)E3;                             // alias: E3 dead after d3
  int* ROOTL  = (int*)E2;                             // alias: E2 dead after d2
  int*   ROOTC = (int*)(small);                       // 64 ints
  int*   U     = (int*)(small + 256);                 // 64*16 ints
  int*   NC    = (int*)(small + 4352);                // 64 ints
  int*   CNT   = (int*)(small + 4608);                // 64*16 ints
  float* SX    = (float*)(small + 8704);              // 64*16 f
  float* SY    = (float*)(small + 12800);             // 64*16 f

  hipMemsetAsync(ROOTC, 0, 256, stream);
  hipMemsetAsync(CNT, 0, 4096, stream);
  hipMemsetAsync(SX, 0, 4096, stream);
  hipMemsetAsync(SY, 0, 4096, stream);

  for (int pass = 0; pass < 2; pass++) {
    const float* x = (pass == 0) ? x1 : x2;
    int base = pass * 32;
    k_conv_e1<<<4608, 256, 0, stream>>>(x, e1w, e1b, E1);
    k_conv_e2<<<576, 256, 0, stream>>>(E1, e2w, e2b, E2);
    k_conv_e3<<<dim3(144, 2), 256, 0, stream>>>(E2, e3w, e3b, E3);
    k_convt_d3<<<576, 256, 0, stream>>>(E3, d3w, d3b, D3);
    k_convt_d2<<<576, 256, 0, stream>>>(D3, E2, d2w, d2b, D2);
    k_convt_d1<<<9216, 256, 0, stream>>>(D2, E1, d1w, d1b, PARENT);
    k_tile_uf<<<dim3(144, 32), 256, 0, stream>>>(PARENT);
    k_border<<<18432, 256, 0, stream>>>(PARENT);
    k_flatten<<<18432, 256, 0, stream>>>(PARENT, ROOTC, ROOTL, base);
    k_select<<<32, 256, 0, stream>>>(ROOTC, ROOTL, U, NC, base);
    k_stats<<<dim3(576, 32), 256, 0, stream>>>(PARENT, U, CNT, SX, SY, base);
  }
  k_final<<<1, 64, 0, stream>>>(U, NC, CNT, SX, SY, w1, b1, w2, b2, w3, b3, (float*)d_out);
}

// Round 5
// 3270.631 us; speedup vs baseline: 4.0302x; 1.1479x over previous
//
#include <hip/hip_runtime.h>
#include <math.h>

// ---------------- problem constants ----------------
#define NIMG 32          // images per pass (x1 pass, x2 pass)
#define SENTI 147456     // H*W sentinel
#define CAPR 36864       // max 8-connected components in 384x384
#define LBG 0x7FFFFFFF   // LDS background marker

// ---------------- global union-find (device-scope safe, used on borders only) ----------------
__device__ __forceinline__ int uf_load(int* P, int i) {
  return __hip_atomic_load(&P[i], __ATOMIC_RELAXED, __HIP_MEMORY_SCOPE_AGENT);
}
__device__ int uf_find(int* P, int i) {
  int p = uf_load(P, i);
  while (p != i) {
    int gp = uf_load(P, p);
    if (gp != p) atomicMin(&P[i], gp);   // path halving, monotone decreasing => safe
    i = p; p = gp;
  }
  return i;
}
__device__ void uf_union(int* P, int a, int b) {
  while (true) {
    a = uf_find(P, a); b = uf_find(P, b);
    if (a == b) return;
    if (a > b) { int t = a; a = b; b = t; }   // a < b : attach b under a (min root wins)
    int old = atomicMin(&P[b], a);
    if (old == b) return;
    b = old;
  }
}

// ---------------- LDS union-find (tile-local) ----------------
__device__ __forceinline__ int l_load(int* lab, int i) {
  return __hip_atomic_load(&lab[i], __ATOMIC_RELAXED, __HIP_MEMORY_SCOPE_WORKGROUP);
}
__device__ int l_find(int* lab, int i) {
  int p = l_load(lab, i);
  while (p != i) { int gp = l_load(lab, p); i = p; p = gp; }
  return i;
}
__device__ void l_union(int* lab, int a, int b) {
  while (true) {
    a = l_find(lab, a); b = l_find(lab, b);
    if (a == b) return;
    if (a > b) { int t = a; a = b; b = t; }
    int old = atomicMin(&lab[b], a);
    if (old == b) return;
    b = old;
  }
}

// ---------------- conv e1: (32,1,384,384) -> (32,16,192,192), k4 s2 p1 + relu ----------------
__global__ __launch_bounds__(256) void k_conv_e1(
    const float* __restrict__ x, const float* __restrict__ w,
    const float* __restrict__ bias, float* __restrict__ out)
{
  int idx = blockIdx.x * 256 + threadIdx.x;           // 32*192*192
  int ox = idx % 192; int t = idx / 192; int oy = t % 192; int img = t / 192;
  const float* xi = x + (size_t)img * 147456;
  float acc[16];
#pragma unroll
  for (int c = 0; c < 16; c++) acc[c] = bias[c];
#pragma unroll
  for (int ky = 0; ky < 4; ky++) {
    int iy = 2 * oy + ky - 1;
    if (iy < 0 || iy >= 384) continue;
    const float* row = xi + iy * 384;
#pragma unroll
    for (int kx = 0; kx < 4; kx++) {
      int ix = 2 * ox + kx - 1;
      if (ix < 0 || ix >= 384) continue;
      float v = row[ix];
#pragma unroll
      for (int c = 0; c < 16; c++) acc[c] = fmaf(v, w[c * 16 + ky * 4 + kx], acc[c]);
    }
  }
  size_t base = (size_t)img * 589824 + (size_t)oy * 192 + ox;   // 16*36864
#pragma unroll
  for (int c = 0; c < 16; c++) out[base + (size_t)c * 36864] = fmaxf(acc[c], 0.f);
}

// ---------------- conv e2: (32,16,192,192) -> (32,32,96,96) ----------------
__global__ __launch_bounds__(256) void k_conv_e2(
    const float* __restrict__ in, const float* __restrict__ w,
    const float* __restrict__ bias, float* __restrict__ out)
{
  int idx = blockIdx.x * 256 + threadIdx.x;           // 32*96*48 (2 cols/thread)
  int p = idx % 48; int t = idx / 48; int oy = t % 96; int img = t / 96;
  const float* xin = in + (size_t)img * 589824;
  float accA[32], accB[32];
#pragma unroll
  for (int c = 0; c < 32; c++) { float bv = bias[c]; accA[c] = bv; accB[c] = bv; }
#pragma unroll 1
  for (int ci = 0; ci < 16; ci++) {
    const float* xc = xin + (size_t)ci * 36864;
#pragma unroll
    for (int ky = 0; ky < 4; ky++) {
      int iy = 2 * oy + ky - 1;
      float xv[6];
      if (iy >= 0 && iy < 192) {
        const float* row = xc + iy * 192;
        int c0 = 4 * p - 1;
#pragma unroll
        for (int u = 0; u < 6; u++) {
          int ix = c0 + u;
          xv[u] = (ix >= 0 && ix < 192) ? row[ix] : 0.f;
        }
      } else {
#pragma unroll
        for (int u = 0; u < 6; u++) xv[u] = 0.f;
      }
#pragma unroll
      for (int co = 0; co < 32; co++) {
        float4 wv = *(const float4*)(w + ((size_t)co * 16 + ci) * 16 + ky * 4);
        accA[co] = fmaf(xv[3], wv.w, fmaf(xv[2], wv.z, fmaf(xv[1], wv.y, fmaf(xv[0], wv.x, accA[co]))));
        accB[co] = fmaf(xv[5], wv.w, fmaf(xv[4], wv.z, fmaf(xv[3], wv.y, fmaf(xv[2], wv.x, accB[co]))));
      }
    }
  }
  size_t base = (size_t)img * 294912 + (size_t)oy * 96 + 2 * p;  // 32*9216
#pragma unroll
  for (int co = 0; co < 32; co++) {
    float2 v; v.x = fmaxf(accA[co], 0.f); v.y = fmaxf(accB[co], 0.f);
    *(float2*)(out + base + (size_t)co * 9216) = v;
  }
}

// ---------------- conv e3: (32,32,96,96) -> (32,64,48,48), co split in 4 groups of 16 ----------------
// cog 0..3: 576 blocks total (was 288) -> 2.25 waves/SIMD for latency hiding.
__global__ __launch_bounds__(256) void k_conv_e3(
    const float* __restrict__ in, const float* __restrict__ w,
    const float* __restrict__ bias, float* __restrict__ out)
{
  int idx = blockIdx.x * 256 + threadIdx.x;           // 32*48*24
  int cog = blockIdx.y;                               // 0..3 -> co groups of 16
  int p = idx % 24; int t = idx / 24; int oy = t % 48; int img = t / 48;
  const float* xin = in + (size_t)img * 294912;
  float accA[16], accB[16];
#pragma unroll
  for (int c = 0; c < 16; c++) { float bv = bias[cog * 16 + c]; accA[c] = bv; accB[c] = bv; }
#pragma unroll 1
  for (int ci = 0; ci < 32; ci++) {
    const float* xc = xin + (size_t)ci * 9216;
#pragma unroll
    for (int ky = 0; ky < 4; ky++) {
      int iy = 2 * oy + ky - 1;
      float xv[6];
      if (iy >= 0 && iy < 96) {
        const float* row = xc + iy * 96;
        int c0 = 4 * p - 1;
#pragma unroll
        for (int u = 0; u < 6; u++) {
          int ix = c0 + u;
          xv[u] = (ix >= 0 && ix < 96) ? row[ix] : 0.f;
        }
      } else {
#pragma unroll
        for (int u = 0; u < 6; u++) xv[u] = 0.f;
      }
#pragma unroll
      for (int co = 0; co < 16; co++) {
        float4 wv = *(const float4*)(w + ((size_t)(cog * 16 + co) * 32 + ci) * 16 + ky * 4);
        accA[co] = fmaf(xv[3], wv.w, fmaf(xv[2], wv.z, fmaf(xv[1], wv.y, fmaf(xv[0], wv.x, accA[co]))));
        accB[co] = fmaf(xv[5], wv.w, fmaf(xv[4], wv.z, fmaf(xv[3], wv.y, fmaf(xv[2], wv.x, accB[co]))));
      }
    }
  }
  size_t base = (size_t)img * 147456 + (size_t)(cog * 16) * 2304 + (size_t)oy * 48 + 2 * p;
#pragma unroll
  for (int co = 0; co < 16; co++) {
    float2 v; v.x = fmaxf(accA[co], 0.f); v.y = fmaxf(accB[co], 0.f);
    *(float2*)(out + base + (size_t)co * 2304) = v;
  }
}

// ---------------- convT d3: (32,64,48,48) -> (32,32,96,96), w (64,32,4,4) ----------------
__global__ __launch_bounds__(256) void k_convt_d3(
    const float* __restrict__ in, const float* __restrict__ w,
    const float* __restrict__ bias, float* __restrict__ out)
{
  int idx = blockIdx.x * 256 + threadIdx.x;           // 32*96*48
  int p = idx % 48; int t = idx / 48; int oy = t % 96; int img = t / 96;
  int iy1 = (oy + 1) >> 1; int iy0 = iy1 - 1;
  int ky1 = (oy + 1) - 2 * iy1; int ky0 = ky1 + 2;    // ky1 in {0,1}
  bool v1 = (iy1 < 48), v0 = (iy0 >= 0);
  bool pm = (p > 0), pp = (p < 47);
  float accA[32], accB[32];
#pragma unroll
  for (int c = 0; c < 32; c++) { float bv = bias[c]; accA[c] = bv; accB[c] = bv; }
#pragma unroll 1
  for (int ci = 0; ci < 64; ci++) {
    const float* xc = in + (size_t)img * 147456 + (size_t)ci * 2304;
    const float* r1 = xc + iy1 * 48; const float* r0 = xc + iy0 * 48;
    float x1m = (v1 && pm) ? r1[p - 1] : 0.f;
    float x1c = v1 ? r1[p] : 0.f;
    float x1p = (v1 && pp) ? r1[p + 1] : 0.f;
    float x0m = (v0 && pm) ? r0[p - 1] : 0.f;
    float x0c = v0 ? r0[p] : 0.f;
    float x0p = (v0 && pp) ? r0[p + 1] : 0.f;
    const float* wb = w + (size_t)ci * 512;           // ci*32*16
#pragma unroll
    for (int co = 0; co < 32; co++) {
      float4 wv1 = *(const float4*)(wb + co * 16 + ky1 * 4);
      float4 wv0 = *(const float4*)(wb + co * 16 + ky0 * 4);
      accA[co] += x1c * wv1.y + x1m * wv1.w + x0c * wv0.y + x0m * wv0.w;
      accB[co] += x1p * wv1.x + x1c * wv1.z + x0p * wv0.x + x0c * wv0.z;
    }
  }
  size_t base = (size_t)img * 294912 + (size_t)oy * 96 + 2 * p;
#pragma unroll
  for (int co = 0; co < 32; co++) {
    float2 v; v.x = fmaxf(accA[co], 0.f); v.y = fmaxf(accB[co], 0.f);
    *(float2*)(out + base + (size_t)co * 9216) = v;
  }
}

// ---------------- convT d2 (dual src): [D3 | E2] (32,64,96,96) -> (32,16,192,192), w (64,16,4,4) ----------------
// 8 output cols per thread (4 pairs): amortizes weight loads 4x vs 2-col version.
__global__ __launch_bounds__(256) void k_convt_d2(
    const float* __restrict__ d3, const float* __restrict__ e2,
    const float* __restrict__ w, const float* __restrict__ bias,
    float* __restrict__ out)
{
  int idx = blockIdx.x * 256 + threadIdx.x;           // 32*192*24
  int pg = idx % 24; int t = idx / 24; int oy = t % 192; int img = t / 192;
  int iy1 = (oy + 1) >> 1; int iy0 = iy1 - 1;
  int ky1 = (oy + 1) - 2 * iy1; int ky0 = ky1 + 2;    // ky1 in {0,1}
  bool v1 = (iy1 < 96), v0 = (iy0 >= 0);
  int c0 = 4 * pg - 1;                                // input col base (6 cols used)
  float acc[16][8];
#pragma unroll
  for (int co = 0; co < 16; co++) {
    float bv = bias[co];
#pragma unroll
    for (int j = 0; j < 8; j++) acc[co][j] = bv;
  }
  for (int half = 0; half < 2; half++) {
    const float* src = (half == 0) ? d3 : e2;
#pragma unroll 1
    for (int ci = 0; ci < 32; ci++) {
      const float* xc = src + (size_t)img * 294912 + (size_t)ci * 9216;
      const float* r1 = xc + iy1 * 96; const float* r0 = xc + iy0 * 96;
      float x1[6], x0[6];
#pragma unroll
      for (int u = 0; u < 6; u++) {
        int ix = c0 + u;
        bool cb = (ix >= 0) && (ix < 96);
        x1[u] = (v1 && cb) ? r1[ix] : 0.f;
        x0[u] = (v0 && cb) ? r0[ix] : 0.f;
      }
      const float* wb = w + (size_t)(half * 32 + ci) * 256;  // ci_glob*16*16
#pragma unroll
      for (int co = 0; co < 16; co++) {
        float4 wv1 = *(const float4*)(wb + co * 16 + ky1 * 4);
        float4 wv0 = *(const float4*)(wb + co * 16 + ky0 * 4);
#pragma unroll
        for (int j = 0; j < 4; j++) {                 // output pair j -> cols 8*pg+2j, +1
          acc[co][2 * j]     += x1[j + 1] * wv1.y + x1[j] * wv1.w
                              + x0[j + 1] * wv0.y + x0[j] * wv0.w;
          acc[co][2 * j + 1] += x1[j + 2] * wv1.x + x1[j + 1] * wv1.z
                              + x0[j + 2] * wv0.x + x0[j + 1] * wv0.z;
        }
      }
    }
  }
  size_t base = (size_t)img * 589824 + (size_t)oy * 192 + 8 * pg;  // 16*36864
#pragma unroll
  for (int co = 0; co < 16; co++) {
    float4 a, b;
    a.x = fmaxf(acc[co][0], 0.f); a.y = fmaxf(acc[co][1], 0.f);
    a.z = fmaxf(acc[co][2], 0.f); a.w = fmaxf(acc[co][3], 0.f);
    b.x = fmaxf(acc[co][4], 0.f); b.y = fmaxf(acc[co][5], 0.f);
    b.z = fmaxf(acc[co][6], 0.f); b.w = fmaxf(acc[co][7], 0.f);
    *(float4*)(out + base + (size_t)co * 36864)     = a;
    *(float4*)(out + base + (size_t)co * 36864 + 4) = b;
  }
}

// ---------------- convT d1 (dual src) + sigmoid-threshold -> parent init ----------------
__global__ __launch_bounds__(256) void k_convt_d1(
    const float* __restrict__ d2, const float* __restrict__ e1,
    const float* __restrict__ w, const float* __restrict__ bias,
    int* __restrict__ parent)
{
  int idx = blockIdx.x * 256 + threadIdx.x;           // 32*384*192
  int p = idx % 192; int t = idx / 192; int oy = t % 384; int img = t / 384;
  int iy1 = (oy + 1) >> 1; int iy0 = iy1 - 1;
  int ky1 = (oy + 1) - 2 * iy1; int ky0 = ky1 + 2;
  bool v1 = (iy1 < 192), v0 = (iy0 >= 0);
  bool pm = (p > 0), pp = (p < 191);
  float zA = bias[0], zB = bias[0];
  for (int half = 0; half < 2; half++) {
    const float* src = (half == 0) ? d2 : e1;
#pragma unroll 1
    for (int ci = 0; ci < 16; ci++) {
      const float* xc = src + (size_t)img * 589824 + (size_t)ci * 36864;
      const float* r1 = xc + iy1 * 192; const float* r0 = xc + iy0 * 192;
      float x1m = (v1 && pm) ? r1[p - 1] : 0.f;
      float x1c = v1 ? r1[p] : 0.f;
      float x1p = (v1 && pp) ? r1[p + 1] : 0.f;
      float x0m = (v0 && pm) ? r0[p - 1] : 0.f;
      float x0c = v0 ? r0[p] : 0.f;
      float x0p = (v0 && pp) ? r0[p + 1] : 0.f;
      const float* wb = w + (size_t)(half * 16 + ci) * 16;   // (32,1,4,4)
      float4 wv1 = *(const float4*)(wb + ky1 * 4);
      float4 wv0 = *(const float4*)(wb + ky0 * 4);
      zA += x1c * wv1.y + x1m * wv1.w + x0c * wv0.y + x0m * wv0.w;
      zB += x1p * wv1.x + x1c * wv1.z + x0p * wv0.x + x0c * wv0.z;
    }
  }
  // sigmoid(z) > 0.75  <=>  z > ln(3)
  const float LN3 = 1.0986122886681098f;
  int* P = parent + (size_t)img * SENTI;
  int pixA = oy * 384 + 2 * p;
  P[pixA]     = (zA > LN3) ? pixA : SENTI;
  P[pixA + 1] = (zB > LN3) ? (pixA + 1) : SENTI;
}

// ---------------- tile-local CCL: 32x32 tiles, union-find in LDS ----------------
__global__ __launch_bounds__(256) void k_tile_uf(int* __restrict__ parent)
{
  __shared__ int lab[1024];
  int img = blockIdx.y;
  int tile = blockIdx.x;                              // 0..143
  int tx = tile % 12, ty = tile / 12;
  int tid = threadIdx.x;
  int* P = parent + (size_t)img * SENTI;
  int gbase = (ty * 32) * 384 + tx * 32;
  bool fg[4];
#pragma unroll
  for (int s = 0; s < 4; s++) {
    int c = tid + s * 256;
    int ly = c >> 5, lx = c & 31;
    int v = P[gbase + ly * 384 + lx];
    fg[s] = (v < SENTI);
    lab[c] = fg[s] ? c : LBG;
  }
  __syncthreads();
#pragma unroll
  for (int s = 0; s < 4; s++) {
    int c = tid + s * 256;
    if (!fg[s]) continue;
    int ly = c >> 5, lx = c & 31;
    if (lx > 0              && l_load(lab, c - 1)  != LBG) l_union(lab, c, c - 1);
    if (ly > 0) {
      if (                     l_load(lab, c - 32) != LBG) l_union(lab, c, c - 32);
      if (lx > 0            && l_load(lab, c - 33) != LBG) l_union(lab, c, c - 33);
      if (lx < 31           && l_load(lab, c - 31) != LBG) l_union(lab, c, c - 31);
    }
  }
  __syncthreads();
#pragma unroll
  for (int s = 0; s < 4; s++) {
    int c = tid + s * 256;
    if (!fg[s]) continue;
    int rc = c, q = lab[rc];
    while (q != rc) { rc = q; q = lab[rc]; }          // structure frozen after barrier
    int rly = rc >> 5, rlx = rc & 31;
    int ly = c >> 5, lx = c & 31;
    P[gbase + ly * 384 + lx] = gbase + rly * 384 + rlx;
  }
}

// ---------------- border merge: unions only across 32-aligned tile edges ----------------
__global__ __launch_bounds__(256) void k_border(int* __restrict__ parent)
{
  int idx = blockIdx.x * 256 + threadIdx.x;           // 32*147456
  int img = idx / SENTI; int p = idx - img * SENTI;
  int* P = parent + (size_t)img * SENTI;
  int x = p % 384; int y = p / 384;
  bool bx = ((x & 31) == 0) && x > 0;
  bool by = ((y & 31) == 0) && y > 0;
  if (!bx && !by) return;
  if (P[p] >= SENTI) return;
  if (bx) {
    if (            P[p - 1]   < SENTI) uf_union(P, p, p - 1);
    if (y > 0   &&  P[p - 385] < SENTI) uf_union(P, p, p - 385);
    if (y < 383 &&  P[p + 383] < SENTI) uf_union(P, p, p + 383);
  }
  if (by) {
    if (            P[p - 384] < SENTI) uf_union(P, p, p - 384);
    if (x > 0   &&  P[p - 385] < SENTI) uf_union(P, p, p - 385);
    if (x < 383 &&  P[p - 383] < SENTI) uf_union(P, p, p - 383);
  }
}

// ---------------- flatten + per-block root aggregation (one global atomic per block) ----------------
__global__ __launch_bounds__(256) void k_flatten(
    int* __restrict__ parent, int* __restrict__ rootCnt,
    int* __restrict__ rootList, int base)
{
  __shared__ int lcnt;
  __shared__ int lbase;
  __shared__ int llist[256];
  int tid = threadIdx.x;
  if (tid == 0) lcnt = 0;
  __syncthreads();
  int idx = blockIdx.x * 256 + tid;
  int img = idx / SENTI; int p = idx - img * SENTI;   // 576 blocks per image (exact)
  int* P = parent + (size_t)img * SENTI;
  int v = P[p];
  if (v < SENTI) {
    int r = v, q = P[r];
    while (q != r) { r = q; q = P[r]; }               // labels strictly decrease -> terminates
    P[p] = r;
    if (r == p) {
      int s = atomicAdd(&lcnt, 1);                    // LDS atomic: cheap, intra-CU
      llist[s] = p;
    }
  }
  __syncthreads();
  int n = lcnt;
  if (n > 0) {
    if (tid == 0) lbase = atomicAdd(&rootCnt[base + img], n);   // ONE global RMW per block
    __syncthreads();
    if (tid < n) rootList[(size_t)img * CAPR + lbase + tid] = llist[tid];  // coalesced
  }
}

// ---------------- select K smallest roots per image ----------------
__global__ __launch_bounds__(256) void k_select(
    const int* __restrict__ rootCnt, const int* __restrict__ rootList,
    int* __restrict__ U, int* __restrict__ NC, int base)
{
  int img = blockIdx.x; int tid = threadIdx.x;
  __shared__ int sv[256];
  int m = rootCnt[base + img]; if (m > CAPR) m = CAPR;
  const int* rl = rootList + (size_t)img * CAPR;
  int prev = -1;
  for (int k = 0; k < 16; k++) {
    int best = SENTI;
    for (int i = tid; i < m; i += 256) {
      int v = rl[i];
      if (v > prev && v < best) best = v;
    }
    sv[tid] = best; __syncthreads();
    for (int s = 128; s > 0; s >>= 1) {
      if (tid < s) sv[tid] = min(sv[tid], sv[tid + s]);
      __syncthreads();
    }
    int sel = sv[0];
    if (tid == 0) U[(base + img) * 16 + k] = sel;
    prev = (sel < SENTI) ? sel : 0x7FFF0000;          // once exhausted, stay SENT
    __syncthreads();
  }
  if (tid == 0) NC[base + img] = (m < 16) ? m : 16;
}

// ---------------- per-component centroid stats ----------------
__global__ __launch_bounds__(256) void k_stats(
    const int* __restrict__ parent, const int* __restrict__ U,
    int* __restrict__ CNT, float* __restrict__ SX, float* __restrict__ SY, int base)
{
  __shared__ int lc[16]; __shared__ float lx[16], ly[16];
  int tid = threadIdx.x;
  if (tid < 16) { lc[tid] = 0; lx[tid] = 0.f; ly[tid] = 0.f; }
  __syncthreads();
  int img = blockIdx.y; int g = base + img;
  int p = blockIdx.x * 256 + tid;                     // 576*256 = 147456
  int lbl = parent[(size_t)img * SENTI + p];
  if (lbl < SENTI) {
    const int* u = U + g * 16;
    int slot = -1;
#pragma unroll
    for (int s = 0; s < 16; s++) if (u[s] == lbl) slot = s;
    if (slot >= 0) {
      atomicAdd(&lc[slot], 1);
      atomicAdd(&lx[slot], (float)(p % 384));
      atomicAdd(&ly[slot], (float)(p / 384));
    }
  }
  __syncthreads();
  if (tid < 16 && lc[tid] > 0) {
    atomicAdd(&CNT[g * 16 + tid], lc[tid]);
    atomicAdd(&SX[g * 16 + tid], lx[tid]);
    atomicAdd(&SY[g * 16 + tid], ly[tid]);
  }
}

// ---------------- polar sort + greedy match + MLP ----------------
__global__ __launch_bounds__(64) void k_final(
    const int* __restrict__ U, const int* __restrict__ NC,
    const int* __restrict__ CNT, const float* __restrict__ SX,
    const float* __restrict__ SY,
    const float* __restrict__ w1, const float* __restrict__ b1,
    const float* __restrict__ w2, const float* __restrict__ b2,
    const float* __restrict__ w3, const float* __restrict__ b3,
    float* __restrict__ out)
{
  int b = threadIdx.x;
  if (b >= 32) return;
  const float INF = __builtin_inff();
  float R[2][16], A[2][16]; int N[2];
  for (int side = 0; side < 2; side++) {
    int img = b + side * 32;
    float rr[16], aa[16], key[16];
    for (int s = 0; s < 16; s++) {
      bool valid = U[img * 16 + s] < SENTI;
      float c = fmaxf((float)CNT[img * 16 + s], 1.f);
      float cx = SX[img * 16 + s] / c, cy = SY[img * 16 + s] / c;
      float dx = cx - 192.f, dy = cy - 192.f;
      rr[s] = sqrtf(dx * dx + dy * dy);
      float ang = atan2f(dy, dx) * 57.29577951308232f;   // rad2deg
      ang = fmodf(ang, 360.f);
      if (ang < 0.f) ang += 360.f;                       // python % semantics
      aa[s] = ang;
      key[s] = valid ? rr[s] : INF;
    }
    bool taken[16];
    for (int s = 0; s < 16; s++) taken[s] = false;
    for (int k = 0; k < 16; k++) {                       // stable selection sort by (key, idx)
      int bi = -1; float bk = 0.f;
      for (int s = 0; s < 16; s++) {
        if (taken[s]) continue;
        if (bi < 0 || key[s] < bk) { bi = s; bk = key[s]; }
      }
      taken[bi] = true;
      bool val = (key[bi] < INF);
      R[side][k] = val ? rr[bi] : 0.f;
      A[side][k] = val ? aa[bi] : 0.f;
    }
    N[side] = NC[img];
  }
  // greedy nearest-radius matching (A = smaller-or-equal set)
  int n1 = N[0], n2 = N[1];
  bool sw = n1 > n2;
  float* rA = sw ? R[1] : R[0];
  float* aA = sw ? A[1] : A[0];
  float* rB = sw ? R[0] : R[1];
  float* aB = sw ? A[0] : A[1];
  int nA = sw ? n2 : n1;
  int nB = sw ? n1 : n2;
  bool used[16];
  for (int s = 0; s < 16; s++) used[s] = false;
  float f[32];
  for (int i = 0; i < 16; i++) {
    bool vi = i < nA;
    float best = 0.f; int j = 0; bool found = false;
    for (int jj = 0; jj < 16; jj++) {
      if (used[jj] || jj >= nB) continue;
      float d = fabsf(rB[jj] - rA[i]);
      if (!found || d < best) { best = d; j = jj; found = true; }
    }
    float dr = rA[i] - rB[j];
    float da = fabsf(sinf((aA[i] - aB[j]) * 0.017453292519943295f));  // deg2rad
    f[2 * i]     = vi ? dr : 0.f;
    f[2 * i + 1] = vi ? da : 0.f;
    if (vi) used[j] = true;
  }
  // MLP 32 -> 32 -> 8 -> 1
  float h1[32];
  for (int jj = 0; jj < 32; jj++) {
    float s = b1[jj];
    for (int k2 = 0; k2 < 32; k2++) s += w1[jj * 32 + k2] * f[k2];
    h1[jj] = fmaxf(s, 0.f);
  }
  float h2[8];
  for (int jj = 0; jj < 8; jj++) {
    float s = b2[jj];
    for (int k2 = 0; k2 < 32; k2++) s += w2[jj * 32 + k2] * h1[k2];
    h2[jj] = fmaxf(s, 0.f);
  }
  float o = b3[0];
  for (int k2 = 0; k2 < 8; k2++) o += w3[k2] * h2[k2];
  out[b] = o;
}

// ---------------- host ----------------
extern "C" void kernel_launch(void* const* d_in, const int* in_sizes, int n_in,
                              void* d_out, int out_size, void* d_ws, size_t ws_size,
                              hipStream_t stream)
{
  (void)in_sizes; (void)n_in; (void)out_size; (void)ws_size;
  const float* x1  = (const float*)d_in[0];
  const float* x2  = (const float*)d_in[1];
  const float* e1w = (const float*)d_in[2];  const float* e1b = (const float*)d_in[3];
  const float* e2w = (const float*)d_in[4];  const float* e2b = (const float*)d_in[5];
  const float* e3w = (const float*)d_in[6];  const float* e3b = (const float*)d_in[7];
  const float* d3w = (const float*)d_in[8];  const float* d3b = (const float*)d_in[9];
  const float* d2w = (const float*)d_in[10]; const float* d2b = (const float*)d_in[11];
  const float* d1w = (const float*)d_in[12]; const float* d1b = (const float*)d_in[13];
  const float* w1  = (const float*)d_in[14]; const float* b1  = (const float*)d_in[15];
  const float* w2  = (const float*)d_in[16]; const float* b2  = (const float*)d_in[17];
  const float* w3  = (const float*)d_in[18]; const float* b3  = (const float*)d_in[19];

  // workspace layout (two half-batch passes; peak ~245.4 MB)
  char* ws = (char*)d_ws;
  float* E1 = (float*)(ws + 0);                       //  75,497,472 B (32,16,192,192)
  float* E2 = (float*)(ws + 75497472);                //  37,748,736 B (32,32,96,96)
  float* E3 = (float*)(ws + 113246208);               //  18,874,368 B (32,64,48,48)
  float* D3 = (float*)(ws + 132120576);               //  37,748,736 B (32,32,96,96)
  float* D2 = (float*)(ws + 169869312);               //  75,497,472 B (32,16,192,192)
  char* small = ws + 245366784;
  int* PARENT = (int*)E3;                             // alias: E3 dead after d3
  int* ROOTL  = (int*)E2;                             // alias: E2 dead after d2
  int*   ROOTC = (int*)(small);                       // 64 ints
  int*   U     = (int*)(small + 256);                 // 64*16 ints
  int*   NC    = (int*)(small + 4352);                // 64 ints
  int*   CNT   = (int*)(small + 4608);                // 64*16 ints
  float* SX    = (float*)(small + 8704);              // 64*16 f
  float* SY    = (float*)(small + 12800);             // 64*16 f

  hipMemsetAsync(ROOTC, 0, 256, stream);
  hipMemsetAsync(CNT, 0, 4096, stream);
  hipMemsetAsync(SX, 0, 4096, stream);
  hipMemsetAsync(SY, 0, 4096, stream);

  for (int pass = 0; pass < 2; pass++) {
    const float* x = (pass == 0) ? x1 : x2;
    int base = pass * 32;
    k_conv_e1<<<4608, 256, 0, stream>>>(x, e1w, e1b, E1);
    k_conv_e2<<<576, 256, 0, stream>>>(E1, e2w, e2b, E2);
    k_conv_e3<<<dim3(144, 4), 256, 0, stream>>>(E2, e3w, e3b, E3);
    k_convt_d3<<<576, 256, 0, stream>>>(E3, d3w, d3b, D3);
    k_convt_d2<<<576, 256, 0, stream>>>(D3, E2, d2w, d2b, D2);
    k_convt_d1<<<9216, 256, 0, stream>>>(D2, E1, d1w, d1b, PARENT);
    k_tile_uf<<<dim3(144, 32), 256, 0, stream>>>(PARENT);
    k_border<<<18432, 256, 0, stream>>>(PARENT);
    k_flatten<<<18432, 256, 0, stream>>>(PARENT, ROOTC, ROOTL, base);
    k_select<<<32, 256, 0, stream>>>(ROOTC, ROOTL, U, NC, base);
    k_stats<<<dim3(576, 32), 256, 0, stream>>>(PARENT, U, CNT, SX, SY, base);
  }
  k_final<<<1, 64, 0, stream>>>(U, NC, CNT, SX, SY, w1, b1, w2, b2, w3, b3, (float*)d_out);
}

// Round 6
// 2857.059 us; speedup vs baseline: 4.6135x; 1.1448x over previous
//
#include <hip/hip_runtime.h>
#include <math.h>

// ---------------- problem constants ----------------
#define NIMG 32          // images per pass (x1 pass, x2 pass)
#define SENTI 147456     // H*W sentinel
#define CAPR 36864       // max 8-connected components in 384x384
#define LBG 0x7FFFFFFF   // LDS background marker

// ---------------- global union-find (device-scope safe, used on borders only) ----------------
__device__ __forceinline__ int uf_load(int* P, int i) {
  return __hip_atomic_load(&P[i], __ATOMIC_RELAXED, __HIP_MEMORY_SCOPE_AGENT);
}
__device__ int uf_find(int* P, int i) {
  int p = uf_load(P, i);
  while (p != i) {
    int gp = uf_load(P, p);
    if (gp != p) atomicMin(&P[i], gp);   // path halving, monotone decreasing => safe
    i = p; p = gp;
  }
  return i;
}
__device__ void uf_union(int* P, int a, int b) {
  while (true) {
    a = uf_find(P, a); b = uf_find(P, b);
    if (a == b) return;
    if (a > b) { int t = a; a = b; b = t; }   // a < b : attach b under a (min root wins)
    int old = atomicMin(&P[b], a);
    if (old == b) return;
    b = old;
  }
}

// ---------------- LDS union-find (tile-local) ----------------
__device__ __forceinline__ int l_load(int* lab, int i) {
  return __hip_atomic_load(&lab[i], __ATOMIC_RELAXED, __HIP_MEMORY_SCOPE_WORKGROUP);
}
__device__ int l_find(int* lab, int i) {
  int p = l_load(lab, i);
  while (p != i) { int gp = l_load(lab, p); i = p; p = gp; }
  return i;
}
__device__ void l_union(int* lab, int a, int b) {
  while (true) {
    a = l_find(lab, a); b = l_find(lab, b);
    if (a == b) return;
    if (a > b) { int t = a; a = b; b = t; }
    int old = atomicMin(&lab[b], a);
    if (old == b) return;
    b = old;
  }
}

// ---------------- conv e1: (32,1,384,384) -> (32,16,192,192), k4 s2 p1 + relu ----------------
__global__ __launch_bounds__(256) void k_conv_e1(
    const float* __restrict__ x, const float* __restrict__ w,
    const float* __restrict__ bias, float* __restrict__ out)
{
  int idx = blockIdx.x * 256 + threadIdx.x;           // 32*192*192
  int ox = idx % 192; int t = idx / 192; int oy = t % 192; int img = t / 192;
  const float* xi = x + (size_t)img * 147456;
  float acc[16];
#pragma unroll
  for (int c = 0; c < 16; c++) acc[c] = bias[c];
#pragma unroll
  for (int ky = 0; ky < 4; ky++) {
    int iy = 2 * oy + ky - 1;
    if (iy < 0 || iy >= 384) continue;
    const float* row = xi + iy * 384;
#pragma unroll
    for (int kx = 0; kx < 4; kx++) {
      int ix = 2 * ox + kx - 1;
      if (ix < 0 || ix >= 384) continue;
      float v = row[ix];
#pragma unroll
      for (int c = 0; c < 16; c++) acc[c] = fmaf(v, w[c * 16 + ky * 4 + kx], acc[c]);
    }
  }
  size_t base = (size_t)img * 589824 + (size_t)oy * 192 + ox;   // 16*36864
#pragma unroll
  for (int c = 0; c < 16; c++) out[base + (size_t)c * 36864] = fmaxf(acc[c], 0.f);
}

// ---------------- conv e2: (32,16,192,192) -> (32,32,96,96) ----------------
__global__ __launch_bounds__(256) void k_conv_e2(
    const float* __restrict__ in, const float* __restrict__ w,
    const float* __restrict__ bias, float* __restrict__ out)
{
  int idx = blockIdx.x * 256 + threadIdx.x;           // 32*96*48 (2 cols/thread)
  int p = idx % 48; int t = idx / 48; int oy = t % 96; int img = t / 96;
  const float* xin = in + (size_t)img * 589824;
  float accA[32], accB[32];
#pragma unroll
  for (int c = 0; c < 32; c++) { float bv = bias[c]; accA[c] = bv; accB[c] = bv; }
#pragma unroll 1
  for (int ci = 0; ci < 16; ci++) {
    const float* xc = xin + (size_t)ci * 36864;
#pragma unroll
    for (int ky = 0; ky < 4; ky++) {
      int iy = 2 * oy + ky - 1;
      float xv[6];
      if (iy >= 0 && iy < 192) {
        const float* row = xc + iy * 192;
        int c0 = 4 * p - 1;
#pragma unroll
        for (int u = 0; u < 6; u++) {
          int ix = c0 + u;
          xv[u] = (ix >= 0 && ix < 192) ? row[ix] : 0.f;
        }
      } else {
#pragma unroll
        for (int u = 0; u < 6; u++) xv[u] = 0.f;
      }
#pragma unroll
      for (int co = 0; co < 32; co++) {
        float4 wv = *(const float4*)(w + ((size_t)co * 16 + ci) * 16 + ky * 4);
        accA[co] = fmaf(xv[3], wv.w, fmaf(xv[2], wv.z, fmaf(xv[1], wv.y, fmaf(xv[0], wv.x, accA[co]))));
        accB[co] = fmaf(xv[5], wv.w, fmaf(xv[4], wv.z, fmaf(xv[3], wv.y, fmaf(xv[2], wv.x, accB[co]))));
      }
    }
  }
  size_t base = (size_t)img * 294912 + (size_t)oy * 96 + 2 * p;  // 32*9216
#pragma unroll
  for (int co = 0; co < 32; co++) {
    float2 v; v.x = fmaxf(accA[co], 0.f); v.y = fmaxf(accB[co], 0.f);
    *(float2*)(out + base + (size_t)co * 9216) = v;
  }
}

// ---------------- conv e3: (32,32,96,96) -> (32,64,48,48), co split in 4 groups of 16 ----------------
// cog 0..3: 576 blocks total (was 288) -> 2.25 waves/SIMD for latency hiding.
__global__ __launch_bounds__(256) void k_conv_e3(
    const float* __restrict__ in, const float* __restrict__ w,
    const float* __restrict__ bias, float* __restrict__ out)
{
  int idx = blockIdx.x * 256 + threadIdx.x;           // 32*48*24
  int cog = blockIdx.y;                               // 0..3 -> co groups of 16
  int p = idx % 24; int t = idx / 24; int oy = t % 48; int img = t / 48;
  const float* xin = in + (size_t)img * 294912;
  float accA[16], accB[16];
#pragma unroll
  for (int c = 0; c < 16; c++) { float bv = bias[cog * 16 + c]; accA[c] = bv; accB[c] = bv; }
#pragma unroll 1
  for (int ci = 0; ci < 32; ci++) {
    const float* xc = xin + (size_t)ci * 9216;
#pragma unroll
    for (int ky = 0; ky < 4; ky++) {
      int iy = 2 * oy + ky - 1;
      float xv[6];
      if (iy >= 0 && iy < 96) {
        const float* row = xc + iy * 96;
        int c0 = 4 * p - 1;
#pragma unroll
        for (int u = 0; u < 6; u++) {
          int ix = c0 + u;
          xv[u] = (ix >= 0 && ix < 96) ? row[ix] : 0.f;
        }
      } else {
#pragma unroll
        for (int u = 0; u < 6; u++) xv[u] = 0.f;
      }
#pragma unroll
      for (int co = 0; co < 16; co++) {
        float4 wv = *(const float4*)(w + ((size_t)(cog * 16 + co) * 32 + ci) * 16 + ky * 4);
        accA[co] = fmaf(xv[3], wv.w, fmaf(xv[2], wv.z, fmaf(xv[1], wv.y, fmaf(xv[0], wv.x, accA[co]))));
        accB[co] = fmaf(xv[5], wv.w, fmaf(xv[4], wv.z, fmaf(xv[3], wv.y, fmaf(xv[2], wv.x, accB[co]))));
      }
    }
  }
  size_t base = (size_t)img * 147456 + (size_t)(cog * 16) * 2304 + (size_t)oy * 48 + 2 * p;
#pragma unroll
  for (int co = 0; co < 16; co++) {
    float2 v; v.x = fmaxf(accA[co], 0.f); v.y = fmaxf(accB[co], 0.f);
    *(float2*)(out + base + (size_t)co * 2304) = v;
  }
}

// ---------------- convT d3: (32,64,48,48) -> (32,32,96,96), w (64,32,4,4) ----------------
// 8 output cols per thread + co split in 4 groups of 8: 9.1 FMA/load at 576 blocks.
__global__ __launch_bounds__(256) void k_convt_d3(
    const float* __restrict__ in, const float* __restrict__ w,
    const float* __restrict__ bias, float* __restrict__ out)
{
  int idx = blockIdx.x * 256 + threadIdx.x;           // 32*96*12
  int cog = blockIdx.y;                               // 0..3 -> co groups of 8
  int pg = idx % 12; int t = idx / 12; int oy = t % 96; int img = t / 96;
  int iy1 = (oy + 1) >> 1; int iy0 = iy1 - 1;
  int ky1 = (oy + 1) - 2 * iy1; int ky0 = ky1 + 2;    // ky1 in {0,1}
  bool v1 = (iy1 < 48), v0 = (iy0 >= 0);
  int c0 = 4 * pg - 1;                                // input col base (6 cols used)
  float acc[8][8];
#pragma unroll
  for (int co = 0; co < 8; co++) {
    float bv = bias[cog * 8 + co];
#pragma unroll
    for (int j = 0; j < 8; j++) acc[co][j] = bv;
  }
#pragma unroll 1
  for (int ci = 0; ci < 64; ci++) {
    const float* xc = in + (size_t)img * 147456 + (size_t)ci * 2304;
    const float* r1 = xc + iy1 * 48; const float* r0 = xc + iy0 * 48;
    float x1[6], x0[6];
#pragma unroll
    for (int u = 0; u < 6; u++) {
      int ix = c0 + u;
      bool cb = (ix >= 0) && (ix < 48);
      x1[u] = (v1 && cb) ? r1[ix] : 0.f;
      x0[u] = (v0 && cb) ? r0[ix] : 0.f;
    }
    const float* wb = w + (size_t)ci * 512;           // ci*32*16
#pragma unroll
    for (int co = 0; co < 8; co++) {
      float4 wv1 = *(const float4*)(wb + (cog * 8 + co) * 16 + ky1 * 4);
      float4 wv0 = *(const float4*)(wb + (cog * 8 + co) * 16 + ky0 * 4);
#pragma unroll
      for (int j = 0; j < 4; j++) {                   // output pair j -> cols 8*pg+2j, +1
        acc[co][2 * j]     += x1[j + 1] * wv1.y + x1[j] * wv1.w
                            + x0[j + 1] * wv0.y + x0[j] * wv0.w;
        acc[co][2 * j + 1] += x1[j + 2] * wv1.x + x1[j + 1] * wv1.z
                            + x0[j + 2] * wv0.x + x0[j + 1] * wv0.z;
      }
    }
  }
  size_t base = (size_t)img * 294912 + (size_t)(cog * 8) * 9216 + (size_t)oy * 96 + 8 * pg;
#pragma unroll
  for (int co = 0; co < 8; co++) {
    float4 a, b;
    a.x = fmaxf(acc[co][0], 0.f); a.y = fmaxf(acc[co][1], 0.f);
    a.z = fmaxf(acc[co][2], 0.f); a.w = fmaxf(acc[co][3], 0.f);
    b.x = fmaxf(acc[co][4], 0.f); b.y = fmaxf(acc[co][5], 0.f);
    b.z = fmaxf(acc[co][6], 0.f); b.w = fmaxf(acc[co][7], 0.f);
    *(float4*)(out + base + (size_t)co * 9216)     = a;
    *(float4*)(out + base + (size_t)co * 9216 + 4) = b;
  }
}

// ---------------- convT d2 (dual src): [D3 | E2] (32,64,96,96) -> (32,16,192,192), w (64,16,4,4) ----------------
// 8 output cols per thread (4 pairs): amortizes weight loads 4x vs 2-col version.
__global__ __launch_bounds__(256) void k_convt_d2(
    const float* __restrict__ d3, const float* __restrict__ e2,
    const float* __restrict__ w, const float* __restrict__ bias,
    float* __restrict__ out)
{
  int idx = blockIdx.x * 256 + threadIdx.x;           // 32*192*24
  int pg = idx % 24; int t = idx / 24; int oy = t % 192; int img = t / 192;
  int iy1 = (oy + 1) >> 1; int iy0 = iy1 - 1;
  int ky1 = (oy + 1) - 2 * iy1; int ky0 = ky1 + 2;    // ky1 in {0,1}
  bool v1 = (iy1 < 96), v0 = (iy0 >= 0);
  int c0 = 4 * pg - 1;                                // input col base (6 cols used)
  float acc[16][8];
#pragma unroll
  for (int co = 0; co < 16; co++) {
    float bv = bias[co];
#pragma unroll
    for (int j = 0; j < 8; j++) acc[co][j] = bv;
  }
  for (int half = 0; half < 2; half++) {
    const float* src = (half == 0) ? d3 : e2;
#pragma unroll 1
    for (int ci = 0; ci < 32; ci++) {
      const float* xc = src + (size_t)img * 294912 + (size_t)ci * 9216;
      const float* r1 = xc + iy1 * 96; const float* r0 = xc + iy0 * 96;
      float x1[6], x0[6];
#pragma unroll
      for (int u = 0; u < 6; u++) {
        int ix = c0 + u;
        bool cb = (ix >= 0) && (ix < 96);
        x1[u] = (v1 && cb) ? r1[ix] : 0.f;
        x0[u] = (v0 && cb) ? r0[ix] : 0.f;
      }
      const float* wb = w + (size_t)(half * 32 + ci) * 256;  // ci_glob*16*16
#pragma unroll
      for (int co = 0; co < 16; co++) {
        float4 wv1 = *(const float4*)(wb + co * 16 + ky1 * 4);
        float4 wv0 = *(const float4*)(wb + co * 16 + ky0 * 4);
#pragma unroll
        for (int j = 0; j < 4; j++) {                 // output pair j -> cols 8*pg+2j, +1
          acc[co][2 * j]     += x1[j + 1] * wv1.y + x1[j] * wv1.w
                              + x0[j + 1] * wv0.y + x0[j] * wv0.w;
          acc[co][2 * j + 1] += x1[j + 2] * wv1.x + x1[j + 1] * wv1.z
                              + x0[j + 2] * wv0.x + x0[j + 1] * wv0.z;
        }
      }
    }
  }
  size_t base = (size_t)img * 589824 + (size_t)oy * 192 + 8 * pg;  // 16*36864
#pragma unroll
  for (int co = 0; co < 16; co++) {
    float4 a, b;
    a.x = fmaxf(acc[co][0], 0.f); a.y = fmaxf(acc[co][1], 0.f);
    a.z = fmaxf(acc[co][2], 0.f); a.w = fmaxf(acc[co][3], 0.f);
    b.x = fmaxf(acc[co][4], 0.f); b.y = fmaxf(acc[co][5], 0.f);
    b.z = fmaxf(acc[co][6], 0.f); b.w = fmaxf(acc[co][7], 0.f);
    *(float4*)(out + base + (size_t)co * 36864)     = a;
    *(float4*)(out + base + (size_t)co * 36864 + 4) = b;
  }
}

// ---------------- convT d1 (dual src) + sigmoid-threshold -> parent init ----------------
__global__ __launch_bounds__(256) void k_convt_d1(
    const float* __restrict__ d2, const float* __restrict__ e1,
    const float* __restrict__ w, const float* __restrict__ bias,
    int* __restrict__ parent)
{
  int idx = blockIdx.x * 256 + threadIdx.x;           // 32*384*192
  int p = idx % 192; int t = idx / 192; int oy = t % 384; int img = t / 384;
  int iy1 = (oy + 1) >> 1; int iy0 = iy1 - 1;
  int ky1 = (oy + 1) - 2 * iy1; int ky0 = ky1 + 2;
  bool v1 = (iy1 < 192), v0 = (iy0 >= 0);
  bool pm = (p > 0), pp = (p < 191);
  float zA = bias[0], zB = bias[0];
  for (int half = 0; half < 2; half++) {
    const float* src = (half == 0) ? d2 : e1;
#pragma unroll 1
    for (int ci = 0; ci < 16; ci++) {
      const float* xc = src + (size_t)img * 589824 + (size_t)ci * 36864;
      const float* r1 = xc + iy1 * 192; const float* r0 = xc + iy0 * 192;
      float x1m = (v1 && pm) ? r1[p - 1] : 0.f;
      float x1c = v1 ? r1[p] : 0.f;
      float x1p = (v1 && pp) ? r1[p + 1] : 0.f;
      float x0m = (v0 && pm) ? r0[p - 1] : 0.f;
      float x0c = v0 ? r0[p] : 0.f;
      float x0p = (v0 && pp) ? r0[p + 1] : 0.f;
      const float* wb = w + (size_t)(half * 16 + ci) * 16;   // (32,1,4,4)
      float4 wv1 = *(const float4*)(wb + ky1 * 4);
      float4 wv0 = *(const float4*)(wb + ky0 * 4);
      zA += x1c * wv1.y + x1m * wv1.w + x0c * wv0.y + x0m * wv0.w;
      zB += x1p * wv1.x + x1c * wv1.z + x0p * wv0.x + x0c * wv0.z;
    }
  }
  // sigmoid(z) > 0.75  <=>  z > ln(3)
  const float LN3 = 1.0986122886681098f;
  int* P = parent + (size_t)img * SENTI;
  int pixA = oy * 384 + 2 * p;
  P[pixA]     = (zA > LN3) ? pixA : SENTI;
  P[pixA + 1] = (zB > LN3) ? (pixA + 1) : SENTI;
}

// ---------------- tile-local CCL: 32x32 tiles, union-find in LDS ----------------
__global__ __launch_bounds__(256) void k_tile_uf(int* __restrict__ parent)
{
  __shared__ int lab[1024];
  int img = blockIdx.y;
  int tile = blockIdx.x;                              // 0..143
  int tx = tile % 12, ty = tile / 12;
  int tid = threadIdx.x;
  int* P = parent + (size_t)img * SENTI;
  int gbase = (ty * 32) * 384 + tx * 32;
  bool fg[4];
#pragma unroll
  for (int s = 0; s < 4; s++) {
    int c = tid + s * 256;
    int ly = c >> 5, lx = c & 31;
    int v = P[gbase + ly * 384 + lx];
    fg[s] = (v < SENTI);
    lab[c] = fg[s] ? c : LBG;
  }
  __syncthreads();
#pragma unroll
  for (int s = 0; s < 4; s++) {
    int c = tid + s * 256;
    if (!fg[s]) continue;
    int ly = c >> 5, lx = c & 31;
    if (lx > 0              && l_load(lab, c - 1)  != LBG) l_union(lab, c, c - 1);
    if (ly > 0) {
      if (                     l_load(lab, c - 32) != LBG) l_union(lab, c, c - 32);
      if (lx > 0            && l_load(lab, c - 33) != LBG) l_union(lab, c, c - 33);
      if (lx < 31           && l_load(lab, c - 31) != LBG) l_union(lab, c, c - 31);
    }
  }
  __syncthreads();
#pragma unroll
  for (int s = 0; s < 4; s++) {
    int c = tid + s * 256;
    if (!fg[s]) continue;
    int rc = c, q = lab[rc];
    while (q != rc) { rc = q; q = lab[rc]; }          // structure frozen after barrier
    int rly = rc >> 5, rlx = rc & 31;
    int ly = c >> 5, lx = c & 31;
    P[gbase + ly * 384 + lx] = gbase + rly * 384 + rlx;
  }
}

// ---------------- border merge: unions only across 32-aligned tile edges ----------------
__global__ __launch_bounds__(256) void k_border(int* __restrict__ parent)
{
  int idx = blockIdx.x * 256 + threadIdx.x;           // 32*147456
  int img = idx / SENTI; int p = idx - img * SENTI;
  int* P = parent + (size_t)img * SENTI;
  int x = p % 384; int y = p / 384;
  bool bx = ((x & 31) == 0) && x > 0;
  bool by = ((y & 31) == 0) && y > 0;
  if (!bx && !by) return;
  if (P[p] >= SENTI) return;
  if (bx) {
    if (            P[p - 1]   < SENTI) uf_union(P, p, p - 1);
    if (y > 0   &&  P[p - 385] < SENTI) uf_union(P, p, p - 385);
    if (y < 383 &&  P[p + 383] < SENTI) uf_union(P, p, p + 383);
  }
  if (by) {
    if (            P[p - 384] < SENTI) uf_union(P, p, p - 384);
    if (x > 0   &&  P[p - 385] < SENTI) uf_union(P, p, p - 385);
    if (x < 383 &&  P[p - 383] < SENTI) uf_union(P, p, p - 383);
  }
}

// ---------------- flatten + per-block root aggregation (one global atomic per block) ----------------
__global__ __launch_bounds__(256) void k_flatten(
    int* __restrict__ parent, int* __restrict__ rootCnt,
    int* __restrict__ rootList, int base)
{
  __shared__ int lcnt;
  __shared__ int lbase;
  __shared__ int llist[256];
  int tid = threadIdx.x;
  if (tid == 0) lcnt = 0;
  __syncthreads();
  int idx = blockIdx.x * 256 + tid;
  int img = idx / SENTI; int p = idx - img * SENTI;   // 576 blocks per image (exact)
  int* P = parent + (size_t)img * SENTI;
  int v = P[p];
  if (v < SENTI) {
    int r = v, q = P[r];
    while (q != r) { r = q; q = P[r]; }               // labels strictly decrease -> terminates
    P[p] = r;
    if (r == p) {
      int s = atomicAdd(&lcnt, 1);                    // LDS atomic: cheap, intra-CU
      llist[s] = p;
    }
  }
  __syncthreads();
  int n = lcnt;
  if (n > 0) {
    if (tid == 0) lbase = atomicAdd(&rootCnt[base + img], n);   // ONE global RMW per block
    __syncthreads();
    if (tid < n) rootList[(size_t)img * CAPR + lbase + tid] = llist[tid];  // coalesced
  }
}

// ---------------- select K smallest roots per image ----------------
__global__ __launch_bounds__(256) void k_select(
    const int* __restrict__ rootCnt, const int* __restrict__ rootList,
    int* __restrict__ U, int* __restrict__ NC, int base)
{
  int img = blockIdx.x; int tid = threadIdx.x;
  __shared__ int sv[256];
  int m = rootCnt[base + img]; if (m > CAPR) m = CAPR;
  const int* rl = rootList + (size_t)img * CAPR;
  int prev = -1;
  for (int k = 0; k < 16; k++) {
    int best = SENTI;
    for (int i = tid; i < m; i += 256) {
      int v = rl[i];
      if (v > prev && v < best) best = v;
    }
    sv[tid] = best; __syncthreads();
    for (int s = 128; s > 0; s >>= 1) {
      if (tid < s) sv[tid] = min(sv[tid], sv[tid + s]);
      __syncthreads();
    }
    int sel = sv[0];
    if (tid == 0) U[(base + img) * 16 + k] = sel;
    prev = (sel < SENTI) ? sel : 0x7FFF0000;          // once exhausted, stay SENT
    __syncthreads();
  }
  if (tid == 0) NC[base + img] = (m < 16) ? m : 16;
}

// ---------------- per-component centroid stats ----------------
__global__ __launch_bounds__(256) void k_stats(
    const int* __restrict__ parent, const int* __restrict__ U,
    int* __restrict__ CNT, float* __restrict__ SX, float* __restrict__ SY, int base)
{
  __shared__ int lc[16]; __shared__ float lx[16], ly[16];
  int tid = threadIdx.x;
  if (tid < 16) { lc[tid] = 0; lx[tid] = 0.f; ly[tid] = 0.f; }
  __syncthreads();
  int img = blockIdx.y; int g = base + img;
  int p = blockIdx.x * 256 + tid;                     // 576*256 = 147456
  int lbl = parent[(size_t)img * SENTI + p];
  if (lbl < SENTI) {
    const int* u = U + g * 16;
    int slot = -1;
#pragma unroll
    for (int s = 0; s < 16; s++) if (u[s] == lbl) slot = s;
    if (slot >= 0) {
      atomicAdd(&lc[slot], 1);
      atomicAdd(&lx[slot], (float)(p % 384));
      atomicAdd(&ly[slot], (float)(p / 384));
    }
  }
  __syncthreads();
  if (tid < 16 && lc[tid] > 0) {
    atomicAdd(&CNT[g * 16 + tid], lc[tid]);
    atomicAdd(&SX[g * 16 + tid], lx[tid]);
    atomicAdd(&SY[g * 16 + tid], ly[tid]);
  }
}

// ---------------- polar sort + greedy match + MLP ----------------
__global__ __launch_bounds__(64) void k_final(
    const int* __restrict__ U, const int* __restrict__ NC,
    const int* __restrict__ CNT, const float* __restrict__ SX,
    const float* __restrict__ SY,
    const float* __restrict__ w1, const float* __restrict__ b1,
    const float* __restrict__ w2, const float* __restrict__ b2,
    const float* __restrict__ w3, const float* __restrict__ b3,
    float* __restrict__ out)
{
  int b = threadIdx.x;
  if (b >= 32) return;
  const float INF = __builtin_inff();
  float R[2][16], A[2][16]; int N[2];
  for (int side = 0; side < 2; side++) {
    int img = b + side * 32;
    float rr[16], aa[16], key[16];
    for (int s = 0; s < 16; s++) {
      bool valid = U[img * 16 + s] < SENTI;
      float c = fmaxf((float)CNT[img * 16 + s], 1.f);
      float cx = SX[img * 16 + s] / c, cy = SY[img * 16 + s] / c;
      float dx = cx - 192.f, dy = cy - 192.f;
      rr[s] = sqrtf(dx * dx + dy * dy);
      float ang = atan2f(dy, dx) * 57.29577951308232f;   // rad2deg
      ang = fmodf(ang, 360.f);
      if (ang < 0.f) ang += 360.f;                       // python % semantics
      aa[s] = ang;
      key[s] = valid ? rr[s] : INF;
    }
    bool taken[16];
    for (int s = 0; s < 16; s++) taken[s] = false;
    for (int k = 0; k < 16; k++) {                       // stable selection sort by (key, idx)
      int bi = -1; float bk = 0.f;
      for (int s = 0; s < 16; s++) {
        if (taken[s]) continue;
        if (bi < 0 || key[s] < bk) { bi = s; bk = key[s]; }
      }
      taken[bi] = true;
      bool val = (key[bi] < INF);
      R[side][k] = val ? rr[bi] : 0.f;
      A[side][k] = val ? aa[bi] : 0.f;
    }
    N[side] = NC[img];
  }
  // greedy nearest-radius matching (A = smaller-or-equal set)
  int n1 = N[0], n2 = N[1];
  bool sw = n1 > n2;
  float* rA = sw ? R[1] : R[0];
  float* aA = sw ? A[1] : A[0];
  float* rB = sw ? R[0] : R[1];
  float* aB = sw ? A[0] : A[1];
  int nA = sw ? n2 : n1;
  int nB = sw ? n1 : n2;
  bool used[16];
  for (int s = 0; s < 16; s++) used[s] = false;
  float f[32];
  for (int i = 0; i < 16; i++) {
    bool vi = i < nA;
    float best = 0.f; int j = 0; bool found = false;
    for (int jj = 0; jj < 16; jj++) {
      if (used[jj] || jj >= nB) continue;
      float d = fabsf(rB[jj] - rA[i]);
      if (!found || d < best) { best = d; j = jj; found = true; }
    }
    float dr = rA[i] - rB[j];
    float da = fabsf(sinf((aA[i] - aB[j]) * 0.017453292519943295f));  // deg2rad
    f[2 * i]     = vi ? dr : 0.f;
    f[2 * i + 1] = vi ? da : 0.f;
    if (vi) used[j] = true;
  }
  // MLP 32 -> 32 -> 8 -> 1
  float h1[32];
  for (int jj = 0; jj < 32; jj++) {
    float s = b1[jj];
    for (int k2 = 0; k2 < 32; k2++) s += w1[jj * 32 + k2] * f[k2];
    h1[jj] = fmaxf(s, 0.f);
  }
  float h2[8];
  for (int jj = 0; jj < 8; jj++) {
    float s = b2[jj];
    for (int k2 = 0; k2 < 32; k2++) s += w2[jj * 32 + k2] * h1[k2];
    h2[jj] = fmaxf(s, 0.f);
  }
  float o = b3[0];
  for (int k2 = 0; k2 < 8; k2++) o += w3[k2] * h2[k2];
  out[b] = o;
}

// ---------------- host ----------------
extern "C" void kernel_launch(void* const* d_in, const int* in_sizes, int n_in,
                              void* d_out, int out_size, void* d_ws, size_t ws_size,
                              hipStream_t stream)
{
  (void)in_sizes; (void)n_in; (void)out_size; (void)ws_size;
  const float* x1  = (const float*)d_in[0];
  const float* x2  = (const float*)d_in[1];
  const float* e1w = (const float*)d_in[2];  const float* e1b = (const float*)d_in[3];
  const float* e2w = (const float*)d_in[4];  const float* e2b = (const float*)d_in[5];
  const float* e3w = (const float*)d_in[6];  const float* e3b = (const float*)d_in[7];
  const float* d3w = (const float*)d_in[8];  const float* d3b = (const float*)d_in[9];
  const float* d2w = (const float*)d_in[10]; const float* d2b = (const float*)d_in[11];
  const float* d1w = (const float*)d_in[12]; const float* d1b = (const float*)d_in[13];
  const float* w1  = (const float*)d_in[14]; const float* b1  = (const float*)d_in[15];
  const float* w2  = (const float*)d_in[16]; const float* b2  = (const float*)d_in[17];
  const float* w3  = (const float*)d_in[18]; const float* b3  = (const float*)d_in[19];

  // workspace layout (two half-batch passes; peak ~245.4 MB)
  char* ws = (char*)d_ws;
  float* E1 = (float*)(ws + 0);                       //  75,497,472 B (32,16,192,192)
  float* E2 = (float*)(ws + 75497472);                //  37,748,736 B (32,32,96,96)
  float* E3 = (float*)(ws + 113246208);               //  18,874,368 B (32,64,48,48)
  float* D3 = (float*)(ws + 132120576);               //  37,748,736 B (32,32,96,96)
  float* D2 = (float*)(ws + 169869312);               //  75,497,472 B (32,16,192,192)
  char* small = ws + 245366784;
  int* PARENT = (int*)E3;                             // alias: E3 dead after d3
  int* ROOTL  = (int*)E2;                             // alias: E2 dead after d2
  int*   ROOTC = (int*)(small);                       // 64 ints
  int*   U     = (int*)(small + 256);                 // 64*16 ints
  int*   NC    = (int*)(small + 4352);                // 64 ints
  int*   CNT   = (int*)(small + 4608);                // 64*16 ints
  float* SX    = (float*)(small + 8704);              // 64*16 f
  float* SY    = (float*)(small + 12800);             // 64*16 f

  hipMemsetAsync(ROOTC, 0, 256, stream);
  hipMemsetAsync(CNT, 0, 4096, stream);
  hipMemsetAsync(SX, 0, 4096, stream);
  hipMemsetAsync(SY, 0, 4096, stream);

  for (int pass = 0; pass < 2; pass++) {
    const float* x = (pass == 0) ? x1 : x2;
    int base = pass * 32;
    k_conv_e1<<<4608, 256, 0, stream>>>(x, e1w, e1b, E1);
    k_conv_e2<<<576, 256, 0, stream>>>(E1, e2w, e2b, E2);
    k_conv_e3<<<dim3(144, 4), 256, 0, stream>>>(E2, e3w, e3b, E3);
    k_convt_d3<<<dim3(144, 4), 256, 0, stream>>>(E3, d3w, d3b, D3);
    k_convt_d2<<<576, 256, 0, stream>>>(D3, E2, d2w, d2b, D2);
    k_convt_d1<<<9216, 256, 0, stream>>>(D2, E1, d1w, d1b, PARENT);
    k_tile_uf<<<dim3(144, 32), 256, 0, stream>>>(PARENT);
    k_border<<<18432, 256, 0, stream>>>(PARENT);
    k_flatten<<<18432, 256, 0, stream>>>(PARENT, ROOTC, ROOTL, base);
    k_select<<<32, 256, 0, stream>>>(ROOTC, ROOTL, U, NC, base);
    k_stats<<<dim3(576, 32), 256, 0, stream>>>(PARENT, U, CNT, SX, SY, base);
  }
  k_final<<<1, 64, 0, stream>>>(U, NC, CNT, SX, SY, w1, b1, w2, b2, w3, b3, (float*)d_out);
}